// Round 18
// baseline (781.126 us; speedup 1.0000x reference)
//
#include <hip/hip_runtime.h>
#include <hip/hip_bf16.h>
#include <stdint.h>

#define N_TOK 4096
#define DIM   1024
#define NE    8
#define HID   4096
#define OUTD  1024
#define TOPK  2
#define SLOTS (N_TOK*TOPK)
#define MAXTAB 1280

typedef __bf16 bf16_t;
typedef __attribute__((ext_vector_type(8))) __bf16 bf16x8;
typedef __attribute__((ext_vector_type(4))) __bf16 bf16x4;
typedef __attribute__((ext_vector_type(4))) float  f32x4;

static __device__ __forceinline__ uint32_t pk2(float a, float b) {
    __bf16 x = (__bf16)a, y = (__bf16)b;
    return (uint32_t)__builtin_bit_cast(uint16_t, x) |
          ((uint32_t)__builtin_bit_cast(uint16_t, y) << 16);
}

// ---------------- gating (fp64 logits, top-2, softmax) + x -> bf16 cast ----------------
__global__ __launch_bounds__(512)
void k_gating(const float* __restrict__ x, const float* __restrict__ wg,
              bf16_t* __restrict__ xb,
              int* __restrict__ tki, float* __restrict__ tkg) {
    int n = blockIdx.x * 8 + (threadIdx.x >> 6);
    int lane = threadIdx.x & 63;
    const float* xr = x + (size_t)n * DIM;
    double acc[NE];
#pragma unroll
    for (int e = 0; e < NE; ++e) acc[e] = 0.0;
#pragma unroll
    for (int i = 0; i < 4; ++i) {
        int d0 = i * 256 + lane * 4;
        float4 v = *(const float4*)&xr[d0];
        bf16x4 o;
        o[0] = (__bf16)v.x; o[1] = (__bf16)v.y; o[2] = (__bf16)v.z; o[3] = (__bf16)v.w;
        *(bf16x4*)&xb[(size_t)n * DIM + d0] = o;
        const float* wr = wg + (size_t)d0 * NE;
#pragma unroll
        for (int j = 0; j < 4; ++j) {
            double xv = (double)((&v.x)[j]);
#pragma unroll
            for (int e = 0; e < NE; ++e) acc[e] += xv * (double)wr[j * NE + e];
        }
    }
#pragma unroll
    for (int e = 0; e < NE; ++e)
        for (int off = 32; off > 0; off >>= 1) acc[e] += __shfl_xor(acc[e], off);
    if (lane == 0) {
        int i0 = 0; double v0 = acc[0];
#pragma unroll
        for (int e = 1; e < NE; ++e) if (acc[e] > v0) { v0 = acc[e]; i0 = e; }
        int i1 = -1; double v1 = -1e300;
#pragma unroll
        for (int e = 0; e < NE; ++e) if (e != i0 && acc[e] > v1) { v1 = acc[e]; i1 = e; }
        double e1 = exp(v1 - v0);
        double s = 1.0 + e1;
        tki[n*2]   = i0;  tki[n*2+1] = i1;
        tkg[n*2]   = (float)(1.0 / s);
        tkg[n*2+1] = (float)(e1 / s);
    }
}

// ------- routing: counts/importance/aux/bases + tile tables + XCD ranges + placement -------
__global__ __launch_bounds__(256)
void k_route(const int* __restrict__ tki, const float* __restrict__ tkg,
             int* __restrict__ counts, int* __restrict__ bases,
             int* __restrict__ tab0, int* __restrict__ tab1,
             int* __restrict__ xs0, int* __restrict__ xs1,
             float* __restrict__ aux_out,
             int* __restrict__ tok_ids, int* __restrict__ slotmap) {
    const int e = blockIdx.x, t = threadIdx.x;
    const int wid = t >> 6, lane = t & 63;
    int   lc[NE]; float lg[NE];
#pragma unroll
    for (int k = 0; k < NE; ++k) { lc[k] = 0; lg[k] = 0.f; }
    for (int i = t; i < SLOTS; i += 256) {
        int ee = tki[i]; float gg = tkg[i];
#pragma unroll
        for (int k = 0; k < NE; ++k) if (ee == k) { lc[k]++; lg[k] += gg; }
    }
#pragma unroll
    for (int k = 0; k < NE; ++k)
        for (int off = 32; off > 0; off >>= 1) {
            lc[k] += __shfl_xor(lc[k], off);
            lg[k] += __shfl_xor(lg[k], off);
        }
    __shared__ int   wcI[4][NE];
    __shared__ float wcF[4][NE];
    if (lane == 0)
#pragma unroll
        for (int k = 0; k < NE; ++k) { wcI[wid][k] = lc[k]; wcF[wid][k] = lg[k]; }
    __syncthreads();
    int cnt[NE];
#pragma unroll
    for (int k = 0; k < NE; ++k)
        cnt[k] = wcI[0][k] + wcI[1][k] + wcI[2][k] + wcI[3][k];
    if (e == 0 && t == 0) {
        float gs[NE];
#pragma unroll
        for (int k = 0; k < NE; ++k)
            gs[k] = wcF[0][k] + wcF[1][k] + wcF[2][k] + wcF[3][k];
        float m = 0.f;
        for (int k = 0; k < NE; ++k) m += gs[k];
        m /= (float)NE;
        float var = 0.f;
        for (int k = 0; k < NE; ++k) { float d = gs[k] - m; var += d * d; }
        var /= (float)NE;
        aux_out[0] = 0.01f * var / (m * m + 1e-10f);
        int b = 0;
        for (int k = 0; k < NE; ++k) { counts[k] = cnt[k]; bases[k] = b; b += cnt[k]; }
        // tile tables: BM=128 rows per y-tile; order e -> panel -> y (y fastest)
        int tot0 = 0, tot1 = 0;
        for (int k = 0; k < NE; ++k) {
            int nty = (cnt[k] + 127) >> 7;
            for (int p = 0; p < 16; ++p)
                for (int y = 0; y < nty; ++y)
                    tab0[tot0++] = (k << 16) | (p << 8) | y;
            for (int ks = 0; ks < 4; ++ks)
                for (int p = 0; p < 4; ++p)
                    for (int y = 0; y < nty; ++y)
                        tab1[tot1++] = (k << 16) | (ks << 12) | (p << 8) | y;
        }
        for (int xq = 0; xq <= 8; ++xq) {
            xs0[xq] = (int)(((long long)tot0 * xq) / 8);
            xs1[xq] = (int)(((long long)tot1 * xq) / 8);
        }
    }
    // placement for expert e (ballot prefix-scan, deterministic)
    int run = 0;
    for (int k = 0; k < e; ++k) run += cnt[k];
    __shared__ int wc[4];
    for (int base = 0; base < SLOTS; base += 256) {
        int i = base + t;
        bool f = (tki[i] == e);
        unsigned long long bl = __ballot(f);
        int pre = __popcll(bl & ((1ull << lane) - 1ull));
        if (lane == 0) wc[wid] = __popcll(bl);
        __syncthreads();
        int woff = 0;
#pragma unroll
        for (int u = 0; u < 4; ++u) if (u < wid) woff += wc[u];
        int tot = wc[0] + wc[1] + wc[2] + wc[3];
        if (f) { int s = run + woff + pre; tok_ids[s] = i >> 1; slotmap[i] = s; }
        run += tot;
        __syncthreads();
    }
}

// ---------------- W [E][R][C] fp32 -> Wt [E][C][R] bf16 (R15 geometry) ----------------
__global__ __launch_bounds__(512)
void k_transpose(const float* __restrict__ w1, const float* __restrict__ w2,
                 bf16_t* __restrict__ w1t, bf16_t* __restrict__ w2t) {
    __shared__ bf16_t tT[64][264];        // 33.8 KB
    const int bx = blockIdx.x;
    const float* src; bf16_t* dst; int R, C, ry, cx;
    if (bx < 2048) {
        int e = bx >> 8, rem = bx & 255;
        ry = rem >> 6; cx = rem & 63;
        src = w1 + (size_t)e * DIM * HID; dst = w1t + (size_t)e * DIM * HID;
        R = DIM; C = HID;
    } else {
        int b2 = bx - 2048;
        int e = b2 >> 8, rem = b2 & 255;
        ry = rem >> 4; cx = rem & 15;
        src = w2 + (size_t)e * HID * OUTD; dst = w2t + (size_t)e * HID * OUTD;
        R = HID; C = OUTD;
    }
    const int r0 = ry * 256, c0 = cx * 64;
    const int tx = threadIdx.x & 15;
    const int ta = threadIdx.x >> 4;
#pragma unroll
    for (int p = 0; p < 4; ++p) {
        int r = 2 * ta + 64 * p;
        float4 va = *(const float4*)&src[(size_t)(r0 + r)     * C + c0 + tx * 4];
        float4 vb = *(const float4*)&src[(size_t)(r0 + r + 1) * C + c0 + tx * 4];
#pragma unroll
        for (int j = 0; j < 4; ++j)
            *(uint32_t*)&tT[tx * 4 + j][r] = pk2((&va.x)[j], (&vb.x)[j]);
    }
    __syncthreads();
    const int w = threadIdx.x >> 6, l = threadIdx.x & 63;
    const int ccb = w * 2 + (l >> 5);
    const int rb  = (l & 31) * 8;
#pragma unroll
    for (int q = 0; q < 4; ++q) {
        int cc = q * 16 + ccb;
        bf16x8 o = *(const bf16x8*)&tT[cc][rb];
        *(bf16x8*)&dst[(size_t)(c0 + cc) * R + r0 + rb] = o;
    }
}

// ====== grouped GEMM, 128x256 tile, BK=32, 8 waves (2M x 4N), per-wave 64x64 ======
// R18 = R17 with the workspace-poison fix (cursors now inside the zeroed 256B head).
// Occupancy-2 geometry (72 KiB LDS, <=128 VGPR) -> 2 blocks/CU; per-XCD cursor-stolen
// (e,panel,y-fastest)-ordered tile ranges (balanced to +-1 tile AND B-panel L2-local).
// MODE 0: hbuf[slot] = relu(x_gather @ W1t^T + b1)
// MODE 1 (KSPLIT=4): ybuf[kslot][slot] = h @ W2t^T (+b2 on kslot 0)
template <int MODE>
__global__ __launch_bounds__(512, 4)
void k_gemm(const bf16_t* __restrict__ A,    // MODE0: xb [N][DIM]; MODE1: hbuf [SLOTS][HID]
            const bf16_t* __restrict__ Bt,   // MODE0: w1t [E][HID][DIM]; MODE1: w2t [E][OUTD][HID]
            const float* __restrict__ bias,
            const int* __restrict__ tok_ids,
            const int* __restrict__ bases,
            const int* __restrict__ counts,
            const int* __restrict__ tab,     // tile table
            const int* __restrict__ xs,      // [9] per-XCD ranges
            int* __restrict__ cursor,        // [8] per-XCD steal cursors (zeroed)
            bf16_t* __restrict__ Y) {
    constexpr int KD   = (MODE == 0) ? DIM : HID;
    constexpr int ND   = (MODE == 0) ? HID : OUTD;
    constexpr int KLEN = 1024;                // both modes (MODE1 via KSPLIT=4)
    constexpr int KT   = KLEN / 32;           // 32
    constexpr int BUFE = 12288;               // A 4096 + B 8192 elems (24 KiB)

    const int xcd = blockIdx.x & 7;
    const int beg = xs[xcd], end = xs[xcd + 1];

    extern __shared__ bf16_t lds[];           // 3 * BUFE elems = 72 KiB

    const int t = threadIdx.x, w = t >> 6, L = t & 63;
    const int wm = w >> 2, wn = w & 3;        // 2M x 4N; per-wave out 64x64
    const int lr = L & 15, lq = L >> 4;
    const int srow  = L >> 2;                 // staging row within 16-row GLL group
    const int sslot = L & 3;                  // 16B chunk

    int offA[4], offB[4];
#pragma unroll
    for (int i = 0; i < 4; ++i) {
        int r = wm * 64 + i * 16 + lr;
        offA[i] = r * 32 + ((lq ^ ((r >> 1) & 3)) << 3);
    }
#pragma unroll
    for (int j = 0; j < 4; ++j) {
        int r = wn * 64 + j * 16 + lr;
        offB[j] = 4096 + r * 32 + ((lq ^ ((r >> 1) & 3)) << 3);
    }
    // wave-uniform LDS stage bases: A 1 GLL (16 rows), B 2 GLL (32 rows)
    const int sdstA  = (w * 16) * 32;
    const int sdstB0 = 4096 + (w * 32) * 32;
    const int sdstB1 = 4096 + (w * 32 + 16) * 32;

#define GLL(srcp, dste) __builtin_amdgcn_global_load_lds( \
        (const __attribute__((address_space(1))) uint32_t*)(srcp), \
        (__attribute__((address_space(3))) uint32_t*)(lds + (dste)), 16, 0, 0)
#define STAGE(Tt, bsl) { \
        GLL(aptr  + (Tt) * 32, (bsl) * BUFE + sdstA); \
        GLL(bptr0 + (Tt) * 32, (bsl) * BUFE + sdstB0); \
        GLL(bptr1 + (Tt) * 32, (bsl) * BUFE + sdstB1); }

    __shared__ int sh_ti;
    for (;;) {
        if (t == 0) sh_ti = beg + atomicAdd(&cursor[xcd], 1);
        __syncthreads();                       // also covers prior tile's LDS reads
        const int ti = sh_ti;
        if (ti >= end) break;

        const int ent   = tab[ti];
        const int e     = ent >> 16;
        const int kslot = (ent >> 12) & 15;    // 0 for MODE0
        const int panel = (ent >> 8) & 15;
        const int y     = ent & 255;
        const int ne = counts[e];
        const int b0 = bases[e];
        const int m0 = y * 128, n0 = panel * 256;
        const int koff = kslot * KLEN;
        bf16_t* __restrict__ Yw = (MODE == 0) ? Y : (Y + (size_t)kslot * SLOTS * OUTD);

        // stage pointers
        int arow_i = m0 + w * 16 + srow;
        int arr = (arow_i < ne) ? arow_i : (ne - 1);
        int gka = sslot ^ ((arow_i >> 1) & 3);
        size_t arow = (MODE == 0) ? (size_t)tok_ids[b0 + arr] * KD : (size_t)(b0 + arr) * KD;
        const bf16_t* aptr = A + arow + koff + gka * 8;
        int brow0 = w * 32 + srow;
        int brow1 = w * 32 + 16 + srow;
        const bf16_t* bptr0 = Bt + ((size_t)e * ND + n0 + brow0) * KD + koff + ((sslot ^ ((brow0 >> 1) & 3)) * 8);
        const bf16_t* bptr1 = Bt + ((size_t)e * ND + n0 + brow1) * KD + koff + ((sslot ^ ((brow1 >> 1) & 3)) * 8);

        f32x4 acc[4][4];
#pragma unroll
        for (int i = 0; i < 4; ++i)
#pragma unroll
            for (int j = 0; j < 4; ++j) acc[i][j] = (f32x4){0.f, 0.f, 0.f, 0.f};

        STAGE(0, 0); STAGE(1, 1);

        int cb = 0, nb = 2;
        for (int T = 0; T < KT; ++T) {
            if (T < KT - 1) { asm volatile("s_waitcnt vmcnt(3)" ::: "memory"); }
            else            { asm volatile("s_waitcnt vmcnt(0)" ::: "memory"); }
            __builtin_amdgcn_s_barrier();
            if (T + 2 < KT) STAGE(T + 2, nb);

            bf16x8 fa[4], fb[4];
#pragma unroll
            for (int j = 0; j < 4; ++j) fb[j] = *(const bf16x8*)(lds + cb * BUFE + offB[j]);
#pragma unroll
            for (int i = 0; i < 4; ++i) fa[i] = *(const bf16x8*)(lds + cb * BUFE + offA[i]);
            asm volatile("s_waitcnt lgkmcnt(0)" ::: "memory");
            __builtin_amdgcn_sched_barrier(0);
            __builtin_amdgcn_s_setprio(1);
#pragma unroll
            for (int i = 0; i < 4; ++i)
#pragma unroll
                for (int j = 0; j < 4; ++j)
                    acc[i][j] = __builtin_amdgcn_mfma_f32_16x16x32_bf16(fb[j], fa[i], acc[i][j], 0, 0, 0);
            __builtin_amdgcn_s_setprio(0);

            cb = (cb == 2) ? 0 : cb + 1;
            nb = (nb == 2) ? 0 : nb + 1;
        }

        // epilogue
        const int kbias = (MODE == 0) ? 1 : (kslot == 0 ? 1 : 0);
#pragma unroll
        for (int i = 0; i < 4; ++i) {
            int gm = m0 + wm * 64 + i * 16 + lr;
            if (gm < ne) {
#pragma unroll
                for (int j = 0; j < 4; ++j) {
                    int gn = n0 + wn * 64 + j * 16 + lq * 4;
                    f32x4 bv = *(const f32x4*)&bias[(size_t)e * ND + gn];
                    bf16x4 hv;
#pragma unroll
                    for (int r = 0; r < 4; ++r) {
                        float v = acc[i][j][r];
                        if (kbias) v += bv[r];
                        if (MODE == 0) v = fmaxf(v, 0.f);
                        hv[r] = (__bf16)v;
                    }
                    *(bf16x4*)&Yw[(size_t)(b0 + gm) * ND + gn] = hv;
                }
            }
        }
    }
#undef STAGE
#undef GLL
}

// ---------------- combine: out[n] = g0*sum_s y[s][slot0] + g1*sum_s y[s][slot1] ----------------
__global__ void k_combine(const bf16_t* __restrict__ ybuf,   // [4][SLOTS][OUTD]
                          const int* __restrict__ slotmap,
                          const float* __restrict__ tkg,
                          float* __restrict__ out) {
    int n = blockIdx.x;
    int d = threadIdx.x * 4;
    int s0 = slotmap[2 * n], s1 = slotmap[2 * n + 1];
    float g0 = tkg[2 * n],  g1 = tkg[2 * n + 1];
    f32x4 o = (f32x4){0.f, 0.f, 0.f, 0.f};
#pragma unroll
    for (int s = 0; s < 4; ++s) {
        const bf16_t* ys = ybuf + (size_t)s * SLOTS * OUTD;
        bf16x4 u = *(const bf16x4*)&ys[(size_t)s0 * OUTD + d];
        bf16x4 v = *(const bf16x4*)&ys[(size_t)s1 * OUTD + d];
#pragma unroll
        for (int r = 0; r < 4; ++r)
            o[r] += g0 * (float)u[r] + g1 * (float)v[r];
    }
    *(f32x4*)&out[(size_t)n * OUTD + d] = o;
}

extern "C" void kernel_launch(void* const* d_in, const int* in_sizes, int n_in,
                              void* d_out, int out_size, void* d_ws, size_t ws_size,
                              hipStream_t stream) {
    const float* x  = (const float*)d_in[0];
    const float* wg = (const float*)d_in[1];
    const float* w1 = (const float*)d_in[2];
    const float* b1 = (const float*)d_in[3];
    const float* w2 = (const float*)d_in[4];
    const float* b2 = (const float*)d_in[5];
    float* out = (float*)d_out;

    char* ws = (char*)d_ws;
    // --- R18 FIX: both cursor arrays live inside one 256B zeroed head block ---
    int* cur0 = (int*)(ws + 0);    // 8 ints at [0,32)
    int* cur1 = (int*)(ws + 64);   // 8 ints at [64,96)
    size_t o = 256;
    auto alloc = [&](size_t b) { size_t r = o; o = (o + b + 255) & ~(size_t)255; return r; };
    int*    counts  = (int*)(ws + alloc(NE * 4));
    int*    bases   = (int*)(ws + alloc(NE * 4));
    int*    xs0     = (int*)(ws + alloc(9 * 4));
    int*    xs1     = (int*)(ws + alloc(9 * 4));
    int*    tab0    = (int*)(ws + alloc(MAXTAB * 4));
    int*    tab1    = (int*)(ws + alloc(MAXTAB * 4));
    int*    tki     = (int*)(ws + alloc(SLOTS * 4));
    float*  tkg     = (float*)(ws + alloc(SLOTS * 4));
    int*    tok_ids = (int*)(ws + alloc(SLOTS * 4));
    int*    slotmap = (int*)(ws + alloc(SLOTS * 4));
    bf16_t* xb      = (bf16_t*)(ws + alloc((size_t)N_TOK * DIM * 2));
    size_t  w1t_off = alloc((size_t)NE * HID * DIM * 2);
    bf16_t* w1t     = (bf16_t*)(ws + w1t_off);
    bf16_t* ybuf    = (bf16_t*)(ws + w1t_off);   // [4][SLOTS][OUTD] = 67.1 MB aliases w1t
    bf16_t* w2t     = (bf16_t*)(ws + alloc((size_t)NE * OUTD * HID * 2));
    bf16_t* hbuf    = (bf16_t*)(ws + alloc((size_t)SLOTS * HID * 2));
    (void)ws_size; (void)n_in; (void)in_sizes;

    hipFuncSetAttribute((const void*)&k_gemm<0>, hipFuncAttributeMaxDynamicSharedMemorySize, 73728);
    hipFuncSetAttribute((const void*)&k_gemm<1>, hipFuncAttributeMaxDynamicSharedMemorySize, 73728);

    hipMemsetAsync(ws, 0, 256, stream);   // zero BOTH cursor arrays

    k_gating<<<N_TOK / 8, 512, 0, stream>>>(x, wg, xb, tki, tkg);
    k_route<<<NE, 256, 0, stream>>>(tki, tkg, counts, bases, tab0, tab1, xs0, xs1,
                                    out + (size_t)N_TOK * OUTD, tok_ids, slotmap);
    k_transpose<<<4096, 512, 0, stream>>>(w1, w2, w1t, w2t);

    // 512 blocks = 8 XCDs x 64 slots (2 blocks/CU); per-XCD cursor-stolen tile ranges
    k_gemm<0><<<512, 512, 73728, stream>>>(xb, w1t, b1, tok_ids, bases, counts,
                                           tab0, xs0, cur0, hbuf);
    k_gemm<1><<<512, 512, 73728, stream>>>(hbuf, w2t, b2, tok_ids, bases, counts,
                                           tab1, xs1, cur1, ybuf);

    k_combine<<<N_TOK, 256, 0, stream>>>(ybuf, slotmap, tkg, out);
}

// Round 19
// 556.937 us; speedup vs baseline: 1.4025x; 1.4025x over previous
//
#include <hip/hip_runtime.h>
#include <hip/hip_bf16.h>
#include <stdint.h>

#define N_TOK 4096
#define DIM   1024
#define NE    8
#define HID   4096
#define OUTD  1024
#define TOPK  2
#define SLOTS (N_TOK*TOPK)
#define MAXT0 640   // 16 * max sum(nty), padded multiple of 8
#define MAXT1 320   // 8 * max sum(nty)

typedef __bf16 bf16_t;
typedef __attribute__((ext_vector_type(8))) __bf16 bf16x8;
typedef __attribute__((ext_vector_type(4))) __bf16 bf16x4;
typedef __attribute__((ext_vector_type(4))) float  f32x4;

static __device__ __forceinline__ uint32_t pk2(float a, float b) {
    __bf16 x = (__bf16)a, y = (__bf16)b;
    return (uint32_t)__builtin_bit_cast(uint16_t, x) |
          ((uint32_t)__builtin_bit_cast(uint16_t, y) << 16);
}

// ---------------- gating (fp64 logits, top-2, softmax) + x -> bf16 cast ----------------
__global__ __launch_bounds__(512)
void k_gating(const float* __restrict__ x, const float* __restrict__ wg,
              bf16_t* __restrict__ xb,
              int* __restrict__ tki, float* __restrict__ tkg) {
    int n = blockIdx.x * 8 + (threadIdx.x >> 6);
    int lane = threadIdx.x & 63;
    const float* xr = x + (size_t)n * DIM;
    double acc[NE];
#pragma unroll
    for (int e = 0; e < NE; ++e) acc[e] = 0.0;
#pragma unroll
    for (int i = 0; i < 4; ++i) {
        int d0 = i * 256 + lane * 4;
        float4 v = *(const float4*)&xr[d0];
        bf16x4 o;
        o[0] = (__bf16)v.x; o[1] = (__bf16)v.y; o[2] = (__bf16)v.z; o[3] = (__bf16)v.w;
        *(bf16x4*)&xb[(size_t)n * DIM + d0] = o;
        const float* wr = wg + (size_t)d0 * NE;
#pragma unroll
        for (int j = 0; j < 4; ++j) {
            double xv = (double)((&v.x)[j]);
#pragma unroll
            for (int e = 0; e < NE; ++e) acc[e] += xv * (double)wr[j * NE + e];
        }
    }
#pragma unroll
    for (int e = 0; e < NE; ++e)
        for (int off = 32; off > 0; off >>= 1) acc[e] += __shfl_xor(acc[e], off);
    if (lane == 0) {
        int i0 = 0; double v0 = acc[0];
#pragma unroll
        for (int e = 1; e < NE; ++e) if (acc[e] > v0) { v0 = acc[e]; i0 = e; }
        int i1 = -1; double v1 = -1e300;
#pragma unroll
        for (int e = 0; e < NE; ++e) if (e != i0 && acc[e] > v1) { v1 = acc[e]; i1 = e; }
        double e1 = exp(v1 - v0);
        double s = 1.0 + e1;
        tki[n*2]   = i0;  tki[n*2+1] = i1;
        tkg[n*2]   = (float)(1.0 / s);
        tkg[n*2+1] = (float)(e1 / s);
    }
}

// ------- routing: counts/importance/aux/bases + XCD-interleaved tile tables + placement -------
// NE blocks x 256 thr; deterministic, no atomics. Block 0 t0 builds tile tables ordered
// (e, panel, y-fastest), split into 8 equal ranges, interleaved tab[c*8+r] = range_r[c]
// so same-(blockIdx&7) blocks (same XCD) walk one contiguous panel-sharing range.
__global__ __launch_bounds__(256)
void k_route(const int* __restrict__ tki, const float* __restrict__ tkg,
             int* __restrict__ counts, int* __restrict__ bases,
             int* __restrict__ tab0, int* __restrict__ tab1,
             float* __restrict__ aux_out,
             int* __restrict__ tok_ids, int* __restrict__ slotmap) {
    const int e = blockIdx.x, t = threadIdx.x;
    const int wid = t >> 6, lane = t & 63;
    int   lc[NE]; float lg[NE];
#pragma unroll
    for (int k = 0; k < NE; ++k) { lc[k] = 0; lg[k] = 0.f; }
    for (int i = t; i < SLOTS; i += 256) {
        int ee = tki[i]; float gg = tkg[i];
#pragma unroll
        for (int k = 0; k < NE; ++k) if (ee == k) { lc[k]++; lg[k] += gg; }
    }
#pragma unroll
    for (int k = 0; k < NE; ++k)
        for (int off = 32; off > 0; off >>= 1) {
            lc[k] += __shfl_xor(lc[k], off);
            lg[k] += __shfl_xor(lg[k], off);
        }
    __shared__ int   wcI[4][NE];
    __shared__ float wcF[4][NE];
    if (lane == 0)
#pragma unroll
        for (int k = 0; k < NE; ++k) { wcI[wid][k] = lc[k]; wcF[wid][k] = lg[k]; }
    __syncthreads();
    int cnt[NE];
#pragma unroll
    for (int k = 0; k < NE; ++k)
        cnt[k] = wcI[0][k] + wcI[1][k] + wcI[2][k] + wcI[3][k];
    if (e == 0 && t == 0) {
        float gs[NE];
#pragma unroll
        for (int k = 0; k < NE; ++k)
            gs[k] = wcF[0][k] + wcF[1][k] + wcF[2][k] + wcF[3][k];
        float m = 0.f;
        for (int k = 0; k < NE; ++k) m += gs[k];
        m /= (float)NE;
        float var = 0.f;
        for (int k = 0; k < NE; ++k) { float d = gs[k] - m; var += d * d; }
        var /= (float)NE;
        aux_out[0] = 0.01f * var / (m * m + 1e-10f);
        int b = 0;
        for (int k = 0; k < NE; ++k) { counts[k] = cnt[k]; bases[k] = b; b += cnt[k]; }
        // linear tile lists (e, panel, y-fastest), then 8-way interleave
        int lin0[MAXT0], lin1[MAXT1];
        int tot0 = 0, tot1 = 0;
        for (int k = 0; k < NE; ++k) {
            int nty = (cnt[k] + 255) >> 8;
            for (int p = 0; p < 16; ++p)
                for (int y = 0; y < nty; ++y)
                    lin0[tot0++] = (k << 16) | (p << 8) | y;
            for (int ks = 0; ks < 2; ++ks)
                for (int p = 0; p < 4; ++p)
                    for (int y = 0; y < nty; ++y)
                        lin1[tot1++] = (k << 16) | (ks << 12) | (p << 8) | y;
        }
        for (int i = 0; i < MAXT0; ++i) tab0[i] = -1;
        for (int i = 0; i < MAXT1; ++i) tab1[i] = -1;
        for (int r = 0; r < 8; ++r) {
            int lo = (int)(((long long)tot0 * r) / 8);
            int hi = (int)(((long long)tot0 * (r + 1)) / 8);
            for (int c = 0; c < hi - lo; ++c) tab0[c * 8 + r] = lin0[lo + c];
        }
        for (int r = 0; r < 8; ++r) {
            int lo = (int)(((long long)tot1 * r) / 8);
            int hi = (int)(((long long)tot1 * (r + 1)) / 8);
            for (int c = 0; c < hi - lo; ++c) tab1[c * 8 + r] = lin1[lo + c];
        }
    }
    // placement for expert e (ballot prefix-scan, deterministic)
    int run = 0;
    for (int k = 0; k < e; ++k) run += cnt[k];
    __shared__ int wc[4];
    for (int base = 0; base < SLOTS; base += 256) {
        int i = base + t;
        bool f = (tki[i] == e);
        unsigned long long bl = __ballot(f);
        int pre = __popcll(bl & ((1ull << lane) - 1ull));
        if (lane == 0) wc[wid] = __popcll(bl);
        __syncthreads();
        int woff = 0;
#pragma unroll
        for (int u = 0; u < 4; ++u) if (u < wid) woff += wc[u];
        int tot = wc[0] + wc[1] + wc[2] + wc[3];
        if (f) { int s = run + woff + pre; tok_ids[s] = i >> 1; slotmap[i] = s; }
        run += tot;
        __syncthreads();
    }
}

// ---------------- W [E][R][C] fp32 -> Wt [E][C][R] bf16 (R15 geometry) ----------------
__global__ __launch_bounds__(512)
void k_transpose(const float* __restrict__ w1, const float* __restrict__ w2,
                 bf16_t* __restrict__ w1t, bf16_t* __restrict__ w2t) {
    __shared__ bf16_t tT[64][264];        // 33.8 KB
    const int bx = blockIdx.x;
    const float* src; bf16_t* dst; int R, C, ry, cx;
    if (bx < 2048) {
        int e = bx >> 8, rem = bx & 255;
        ry = rem >> 6; cx = rem & 63;
        src = w1 + (size_t)e * DIM * HID; dst = w1t + (size_t)e * DIM * HID;
        R = DIM; C = HID;
    } else {
        int b2 = bx - 2048;
        int e = b2 >> 8, rem = b2 & 255;
        ry = rem >> 4; cx = rem & 15;
        src = w2 + (size_t)e * HID * OUTD; dst = w2t + (size_t)e * HID * OUTD;
        R = HID; C = OUTD;
    }
    const int r0 = ry * 256, c0 = cx * 64;
    const int tx = threadIdx.x & 15;
    const int ta = threadIdx.x >> 4;
#pragma unroll
    for (int p = 0; p < 4; ++p) {
        int r = 2 * ta + 64 * p;
        float4 va = *(const float4*)&src[(size_t)(r0 + r)     * C + c0 + tx * 4];
        float4 vb = *(const float4*)&src[(size_t)(r0 + r + 1) * C + c0 + tx * 4];
#pragma unroll
        for (int j = 0; j < 4; ++j)
            *(uint32_t*)&tT[tx * 4 + j][r] = pk2((&va.x)[j], (&vb.x)[j]);
    }
    __syncthreads();
    const int w = threadIdx.x >> 6, l = threadIdx.x & 63;
    const int ccb = w * 2 + (l >> 5);
    const int rb  = (l & 31) * 8;
#pragma unroll
    for (int q = 0; q < 4; ++q) {
        int cc = q * 16 + ccb;
        bf16x8 o = *(const bf16x8*)&tT[cc][rb];
        *(bf16x8*)&dst[(size_t)(c0 + cc) * R + r0 + rb] = o;
    }
}

// ====== grouped GEMM, 256x256 tile, BK=32, 8 waves (2M x 4N), per-wave 128x64 ======
// R19 = R16's proven kernel (122us, MfmaUtil 25, 0 conflicts) with ONE change:
// tile picked from the XCD-interleaved table (tab[blockIdx.x]; -1 -> exit), restoring
// B-panel L2 locality (R15's FETCH 77MB) while keeping R16's flat-grid balance.
template <int MODE>
__global__ __launch_bounds__(512, 2)
void k_gemm(const bf16_t* __restrict__ A,    // MODE0: xb [N][DIM]; MODE1: hbuf [SLOTS][HID]
            const bf16_t* __restrict__ Bt,   // MODE0: w1t [E][HID][DIM]; MODE1: w2t [E][OUTD][HID]
            const float* __restrict__ bias,
            const int* __restrict__ tok_ids,
            const int* __restrict__ bases,
            const int* __restrict__ counts,
            const int* __restrict__ tab,     // XCD-interleaved tile table
            bf16_t* __restrict__ Y) {
    constexpr int KD   = (MODE == 0) ? DIM : HID;
    constexpr int ND   = (MODE == 0) ? HID : OUTD;
    constexpr int KLEN = (MODE == 0) ? DIM : (HID / 2);   // 1024 / 2048
    constexpr int KT   = KLEN / 32;                       // 32 / 64
    constexpr int BUFE = 16384;               // A 8192 + B 8192 elems (32 KiB)

    const int ent = tab[blockIdx.x];
    if (ent < 0) return;
    const int e     = ent >> 16;
    const int kslot = (ent >> 12) & 15;       // 0 for MODE0
    const int panel = (ent >> 8) & 15;
    const int y     = ent & 255;
    const int ne = counts[e];
    const int b0 = bases[e];
    const int m0 = y * 256, n0 = panel * 256;
    const int koff = (MODE == 0) ? 0 : kslot * KLEN;
    bf16_t* __restrict__ Yw = (MODE == 0) ? Y : (Y + (size_t)kslot * SLOTS * OUTD);

    extern __shared__ bf16_t lds[];           // 3 * BUFE elems = 96 KiB

    const int t = threadIdx.x, w = t >> 6, L = t & 63;
    const int wm = w >> 2, wn = w & 3;        // 2M x 4N; per-wave out 128x64
    const int lr = L & 15, lq = L >> 4;
    const int srow  = L >> 2;
    const int sslot = L & 3;

    int offA[8], offB[4];
#pragma unroll
    for (int i = 0; i < 8; ++i) {
        int r = wm * 128 + i * 16 + lr;
        offA[i] = r * 32 + ((lq ^ ((r >> 1) & 3)) << 3);
    }
#pragma unroll
    for (int j = 0; j < 4; ++j) {
        int r = wn * 64 + j * 16 + lr;
        offB[j] = 8192 + r * 32 + ((lq ^ ((r >> 1) & 3)) << 3);
    }
    int sdstA[2], sdstB[2];
#pragma unroll
    for (int g = 0; g < 2; ++g) {
        sdstA[g] = (g * 128 + w * 16) * 32;
        sdstB[g] = 8192 + (g * 128 + w * 16) * 32;
    }

#define GLL(srcp, dste) __builtin_amdgcn_global_load_lds( \
        (const __attribute__((address_space(1))) uint32_t*)(srcp), \
        (__attribute__((address_space(3))) uint32_t*)(lds + (dste)), 16, 0, 0)
#define STAGE(Tt, bsl) { \
        _Pragma("unroll") for (int g_ = 0; g_ < 2; ++g_) { \
            GLL(aptr[g_] + (Tt) * 32, (bsl) * BUFE + sdstA[g_]); \
            GLL(bptr[g_] + (Tt) * 32, (bsl) * BUFE + sdstB[g_]); } }

    const bf16_t* aptr[2];
    const bf16_t* bptr[2];
#pragma unroll
    for (int g = 0; g < 2; ++g) {
        int row = g * 128 + w * 16 + srow;
        int gk  = sslot ^ ((row >> 1) & 3);
        int mm = m0 + row;
        int rr = (mm < ne) ? mm : (ne - 1);
        size_t arow = (MODE == 0) ? (size_t)tok_ids[b0 + rr] * KD : (size_t)(b0 + rr) * KD;
        aptr[g] = A + arow + koff + gk * 8;
        bptr[g] = Bt + ((size_t)e * ND + n0 + row) * KD + koff + gk * 8;
    }

    f32x4 acc[8][4];
#pragma unroll
    for (int i = 0; i < 8; ++i)
#pragma unroll
        for (int j = 0; j < 4; ++j) acc[i][j] = (f32x4){0.f, 0.f, 0.f, 0.f};

    STAGE(0, 0); STAGE(1, 1);

    int cb = 0;
    int nb = 2;
    for (int T = 0; T < KT; ++T) {
        if (T < KT - 1) { asm volatile("s_waitcnt vmcnt(4)" ::: "memory"); }
        else            { asm volatile("s_waitcnt vmcnt(0)" ::: "memory"); }
        __builtin_amdgcn_s_barrier();
        if (T + 2 < KT) STAGE(T + 2, nb);

        bf16x8 fb[4], fa[8];
#pragma unroll
        for (int j = 0; j < 4; ++j) fb[j] = *(const bf16x8*)(lds + cb * BUFE + offB[j]);
#pragma unroll
        for (int i = 0; i < 4; ++i) fa[i] = *(const bf16x8*)(lds + cb * BUFE + offA[i]);
        __builtin_amdgcn_sched_barrier(0);
#pragma unroll
        for (int i = 4; i < 8; ++i) fa[i] = *(const bf16x8*)(lds + cb * BUFE + offA[i]);
        __builtin_amdgcn_sched_barrier(0);
        asm volatile("s_waitcnt lgkmcnt(4)" ::: "memory");   // fb + fa0-3 done
        __builtin_amdgcn_sched_barrier(0);
        __builtin_amdgcn_s_setprio(1);
#pragma unroll
        for (int i = 0; i < 4; ++i)
#pragma unroll
            for (int j = 0; j < 4; ++j)
                acc[i][j] = __builtin_amdgcn_mfma_f32_16x16x32_bf16(fb[j], fa[i], acc[i][j], 0, 0, 0);
        __builtin_amdgcn_s_setprio(0);
        asm volatile("s_waitcnt lgkmcnt(0)" ::: "memory");   // fa4-7 done (hidden under mh0)
        __builtin_amdgcn_sched_barrier(0);
        __builtin_amdgcn_s_setprio(1);
#pragma unroll
        for (int i = 4; i < 8; ++i)
#pragma unroll
            for (int j = 0; j < 4; ++j)
                acc[i][j] = __builtin_amdgcn_mfma_f32_16x16x32_bf16(fb[j], fa[i], acc[i][j], 0, 0, 0);
        __builtin_amdgcn_s_setprio(0);

        cb = (cb == 2) ? 0 : cb + 1;
        nb = (nb == 2) ? 0 : nb + 1;
    }

    // ---------------- epilogue: bf16 store ----------------
    const int kbias = (MODE == 0) ? 1 : (kslot == 0 ? 1 : 0);
#pragma unroll
    for (int i = 0; i < 8; ++i) {
        int gm = m0 + wm * 128 + i * 16 + lr;
        if (gm < ne) {
#pragma unroll
            for (int j = 0; j < 4; ++j) {
                int gn = n0 + wn * 64 + j * 16 + lq * 4;
                f32x4 bv = *(const f32x4*)&bias[(size_t)e * ND + gn];
                bf16x4 hv;
#pragma unroll
                for (int r = 0; r < 4; ++r) {
                    float v = acc[i][j][r];
                    if (kbias) v += bv[r];
                    if (MODE == 0) v = fmaxf(v, 0.f);
                    hv[r] = (__bf16)v;
                }
                *(bf16x4*)&Yw[(size_t)(b0 + gm) * ND + gn] = hv;
            }
        }
    }
#undef STAGE
#undef GLL
}

// ---------------- combine: out[n] = g0*(y0a+y0b) + g1*(y1a+y1b) (fp32) ----------------
__global__ void k_combine(const bf16_t* __restrict__ ybuf,   // [2][SLOTS][OUTD]
                          const int* __restrict__ slotmap,
                          const float* __restrict__ tkg,
                          float* __restrict__ out) {
    int n = blockIdx.x;
    int d = threadIdx.x * 4;
    int s0 = slotmap[2 * n], s1 = slotmap[2 * n + 1];
    float g0 = tkg[2 * n],  g1 = tkg[2 * n + 1];
    const bf16_t* y2 = ybuf + (size_t)SLOTS * OUTD;
    bf16x4 a0 = *(const bf16x4*)&ybuf[(size_t)s0 * OUTD + d];
    bf16x4 a1 = *(const bf16x4*)&y2  [(size_t)s0 * OUTD + d];
    bf16x4 c0 = *(const bf16x4*)&ybuf[(size_t)s1 * OUTD + d];
    bf16x4 c1 = *(const bf16x4*)&y2  [(size_t)s1 * OUTD + d];
    f32x4 o;
#pragma unroll
    for (int r = 0; r < 4; ++r)
        o[r] = g0 * ((float)a0[r] + (float)a1[r]) + g1 * ((float)c0[r] + (float)c1[r]);
    *(f32x4*)&out[(size_t)n * OUTD + d] = o;
}

extern "C" void kernel_launch(void* const* d_in, const int* in_sizes, int n_in,
                              void* d_out, int out_size, void* d_ws, size_t ws_size,
                              hipStream_t stream) {
    const float* x  = (const float*)d_in[0];
    const float* wg = (const float*)d_in[1];
    const float* w1 = (const float*)d_in[2];
    const float* b1 = (const float*)d_in[3];
    const float* w2 = (const float*)d_in[4];
    const float* b2 = (const float*)d_in[5];
    float* out = (float*)d_out;

    char* ws = (char*)d_ws;
    size_t o = 0;
    auto alloc = [&](size_t b) { size_t r = o; o = (o + b + 255) & ~(size_t)255; return r; };
    int*    counts  = (int*)(ws + alloc(NE * 4));
    int*    bases   = (int*)(ws + alloc(NE * 4));
    int*    tab0    = (int*)(ws + alloc(MAXT0 * 4));
    int*    tab1    = (int*)(ws + alloc(MAXT1 * 4));
    int*    tki     = (int*)(ws + alloc(SLOTS * 4));
    float*  tkg     = (float*)(ws + alloc(SLOTS * 4));
    int*    tok_ids = (int*)(ws + alloc(SLOTS * 4));
    int*    slotmap = (int*)(ws + alloc(SLOTS * 4));
    bf16_t* xb      = (bf16_t*)(ws + alloc((size_t)N_TOK * DIM * 2));
    size_t  w1t_off = alloc((size_t)NE * HID * DIM * 2);
    bf16_t* w1t     = (bf16_t*)(ws + w1t_off);
    bf16_t* ybuf    = (bf16_t*)(ws + w1t_off);   // [2][SLOTS][OUTD] aliases w1t (dead after GEMM-1)
    bf16_t* w2t     = (bf16_t*)(ws + alloc((size_t)NE * OUTD * HID * 2));
    bf16_t* hbuf    = (bf16_t*)(ws + alloc((size_t)SLOTS * HID * 2));
    (void)ws_size; (void)n_in; (void)in_sizes;

    hipFuncSetAttribute((const void*)&k_gemm<0>, hipFuncAttributeMaxDynamicSharedMemorySize, 98304);
    hipFuncSetAttribute((const void*)&k_gemm<1>, hipFuncAttributeMaxDynamicSharedMemorySize, 98304);

    // deterministic pipeline, no atomics, no ws memset needed
    k_gating<<<N_TOK / 8, 512, 0, stream>>>(x, wg, xb, tki, tkg);
    k_route<<<NE, 256, 0, stream>>>(tki, tkg, counts, bases, tab0, tab1,
                                    out + (size_t)N_TOK * OUTD, tok_ids, slotmap);
    k_transpose<<<4096, 512, 0, stream>>>(w1, w2, w1t, w2t);

    // flat grid, one tile per block; tab entry -1 -> exit
    k_gemm<0><<<MAXT0, 512, 98304, stream>>>(xb, w1t, b1, tok_ids, bases, counts, tab0, hbuf);
    k_gemm<1><<<MAXT1, 512, 98304, stream>>>(hbuf, w2t, b2, tok_ids, bases, counts, tab1, ybuf);

    k_combine<<<N_TOK, 256, 0, stream>>>(ybuf, slotmap, tkg, out);
}

// Round 20
// 365.424 us; speedup vs baseline: 2.1376x; 1.5241x over previous
//
#include <hip/hip_runtime.h>
#include <hip/hip_bf16.h>
#include <stdint.h>

#define N_TOK 4096
#define DIM   1024
#define NE    8
#define HID   4096
#define OUTD  1024
#define TOPK  2
#define SLOTS (N_TOK*TOPK)
#define MAXT0 640   // 16 * max sum(nty), padded multiple of 8
#define MAXT1 320   // 8 * max sum(nty)

typedef __bf16 bf16_t;
typedef __attribute__((ext_vector_type(8))) __bf16 bf16x8;
typedef __attribute__((ext_vector_type(4))) __bf16 bf16x4;
typedef __attribute__((ext_vector_type(4))) float  f32x4;

static __device__ __forceinline__ uint32_t pk2(float a, float b) {
    __bf16 x = (__bf16)a, y = (__bf16)b;
    return (uint32_t)__builtin_bit_cast(uint16_t, x) |
          ((uint32_t)__builtin_bit_cast(uint16_t, y) << 16);
}

// ---------------- gating (fp64 logits, top-2, softmax) + x -> bf16 cast ----------------
__global__ __launch_bounds__(512)
void k_gating(const float* __restrict__ x, const float* __restrict__ wg,
              bf16_t* __restrict__ xb,
              int* __restrict__ tki, float* __restrict__ tkg) {
    int n = blockIdx.x * 8 + (threadIdx.x >> 6);
    int lane = threadIdx.x & 63;
    const float* xr = x + (size_t)n * DIM;
    double acc[NE];
#pragma unroll
    for (int e = 0; e < NE; ++e) acc[e] = 0.0;
#pragma unroll
    for (int i = 0; i < 4; ++i) {
        int d0 = i * 256 + lane * 4;
        float4 v = *(const float4*)&xr[d0];
        bf16x4 o;
        o[0] = (__bf16)v.x; o[1] = (__bf16)v.y; o[2] = (__bf16)v.z; o[3] = (__bf16)v.w;
        *(bf16x4*)&xb[(size_t)n * DIM + d0] = o;
        const float* wr = wg + (size_t)d0 * NE;
#pragma unroll
        for (int j = 0; j < 4; ++j) {
            double xv = (double)((&v.x)[j]);
#pragma unroll
            for (int e = 0; e < NE; ++e) acc[e] += xv * (double)wr[j * NE + e];
        }
    }
#pragma unroll
    for (int e = 0; e < NE; ++e)
        for (int off = 32; off > 0; off >>= 1) acc[e] += __shfl_xor(acc[e], off);
    if (lane == 0) {
        int i0 = 0; double v0 = acc[0];
#pragma unroll
        for (int e = 1; e < NE; ++e) if (acc[e] > v0) { v0 = acc[e]; i0 = e; }
        int i1 = -1; double v1 = -1e300;
#pragma unroll
        for (int e = 0; e < NE; ++e) if (e != i0 && acc[e] > v1) { v1 = acc[e]; i1 = e; }
        double e1 = exp(v1 - v0);
        double s = 1.0 + e1;
        tki[n*2]   = i0;  tki[n*2+1] = i1;
        tkg[n*2]   = (float)(1.0 / s);
        tkg[n*2+1] = (float)(e1 / s);
    }
}

// ------- routing: counts/importance/aux/bases + XCD-interleaved tile tables + placement -------
// NE blocks x 256 thr; deterministic, no atomics, NO local arrays (R20 fix: R19's thread-0
// scratch-array table build cost 250us). Tables built in closed form by all 256 threads of
// block 0: slot i -> (r=i&7, c=i>>3) -> linear li=(tot*r)/8+c -> (e,ks,p,y) via prefix walk.
__global__ __launch_bounds__(256)
void k_route(const int* __restrict__ tki, const float* __restrict__ tkg,
             int* __restrict__ counts, int* __restrict__ bases,
             int* __restrict__ tab0, int* __restrict__ tab1,
             float* __restrict__ aux_out,
             int* __restrict__ tok_ids, int* __restrict__ slotmap) {
    const int e = blockIdx.x, t = threadIdx.x;
    const int wid = t >> 6, lane = t & 63;
    int   lc[NE]; float lg[NE];
#pragma unroll
    for (int k = 0; k < NE; ++k) { lc[k] = 0; lg[k] = 0.f; }
    for (int i = t; i < SLOTS; i += 256) {
        int ee = tki[i]; float gg = tkg[i];
#pragma unroll
        for (int k = 0; k < NE; ++k) if (ee == k) { lc[k]++; lg[k] += gg; }
    }
#pragma unroll
    for (int k = 0; k < NE; ++k)
        for (int off = 32; off > 0; off >>= 1) {
            lc[k] += __shfl_xor(lc[k], off);
            lg[k] += __shfl_xor(lg[k], off);
        }
    __shared__ int   wcI[4][NE];
    __shared__ float wcF[4][NE];
    if (lane == 0)
#pragma unroll
        for (int k = 0; k < NE; ++k) { wcI[wid][k] = lc[k]; wcF[wid][k] = lg[k]; }
    __syncthreads();
    int cnt[NE], nty[NE];
#pragma unroll
    for (int k = 0; k < NE; ++k) {
        cnt[k] = wcI[0][k] + wcI[1][k] + wcI[2][k] + wcI[3][k];
        nty[k] = (cnt[k] + 255) >> 8;
    }
    int tot0 = 0, tot1 = 0;
#pragma unroll
    for (int k = 0; k < NE; ++k) { tot0 += 16 * nty[k]; tot1 += 8 * nty[k]; }

    if (e == 0) {
        if (t == 0) {
            float gs[NE];
#pragma unroll
            for (int k = 0; k < NE; ++k)
                gs[k] = wcF[0][k] + wcF[1][k] + wcF[2][k] + wcF[3][k];
            float m = 0.f;
            for (int k = 0; k < NE; ++k) m += gs[k];
            m /= (float)NE;
            float var = 0.f;
            for (int k = 0; k < NE; ++k) { float d = gs[k] - m; var += d * d; }
            var /= (float)NE;
            aux_out[0] = 0.01f * var / (m * m + 1e-10f);
            int b = 0;
            for (int k = 0; k < NE; ++k) { counts[k] = cnt[k]; bases[k] = b; b += cnt[k]; }
        }
        // parallel closed-form table build (no local arrays, no serialization)
        for (int i = t; i < MAXT0; i += 256) {
            int r = i & 7, c = i >> 3;
            int lo = (int)(((long long)tot0 * r) >> 3);
            int hi = (int)(((long long)tot0 * (r + 1)) >> 3);
            int ent = -1;
            if (c < hi - lo) {
                int li = lo + c, k = 0;
                while (li >= 16 * nty[k]) { li -= 16 * nty[k]; ++k; }   // k<NE guaranteed
                int p = li / nty[k], y = li - p * nty[k];
                ent = (k << 16) | (p << 8) | y;
            }
            tab0[i] = ent;
        }
        for (int i = t; i < MAXT1; i += 256) {
            int r = i & 7, c = i >> 3;
            int lo = (int)(((long long)tot1 * r) >> 3);
            int hi = (int)(((long long)tot1 * (r + 1)) >> 3);
            int ent = -1;
            if (c < hi - lo) {
                int li = lo + c, k = 0;
                while (li >= 8 * nty[k]) { li -= 8 * nty[k]; ++k; }
                int ks = li / (4 * nty[k]);
                int r2 = li - ks * 4 * nty[k];
                int p  = r2 / nty[k], y = r2 - p * nty[k];
                ent = (k << 16) | (ks << 12) | (p << 8) | y;
            }
            tab1[i] = ent;
        }
    }
    // placement for expert e (ballot prefix-scan, deterministic)
    int run = 0;
    for (int k = 0; k < e; ++k) run += cnt[k];
    __shared__ int wc[4];
    for (int base = 0; base < SLOTS; base += 256) {
        int i = base + t;
        bool f = (tki[i] == e);
        unsigned long long bl = __ballot(f);
        int pre = __popcll(bl & ((1ull << lane) - 1ull));
        if (lane == 0) wc[wid] = __popcll(bl);
        __syncthreads();
        int woff = 0;
#pragma unroll
        for (int u = 0; u < 4; ++u) if (u < wid) woff += wc[u];
        int tot = wc[0] + wc[1] + wc[2] + wc[3];
        if (f) { int s = run + woff + pre; tok_ids[s] = i >> 1; slotmap[i] = s; }
        run += tot;
        __syncthreads();
    }
}

// ---------------- W [E][R][C] fp32 -> Wt [E][C][R] bf16 (R15 geometry) ----------------
__global__ __launch_bounds__(512)
void k_transpose(const float* __restrict__ w1, const float* __restrict__ w2,
                 bf16_t* __restrict__ w1t, bf16_t* __restrict__ w2t) {
    __shared__ bf16_t tT[64][264];        // 33.8 KB
    const int bx = blockIdx.x;
    const float* src; bf16_t* dst; int R, C, ry, cx;
    if (bx < 2048) {
        int e = bx >> 8, rem = bx & 255;
        ry = rem >> 6; cx = rem & 63;
        src = w1 + (size_t)e * DIM * HID; dst = w1t + (size_t)e * DIM * HID;
        R = DIM; C = HID;
    } else {
        int b2 = bx - 2048;
        int e = b2 >> 8, rem = b2 & 255;
        ry = rem >> 4; cx = rem & 15;
        src = w2 + (size_t)e * HID * OUTD; dst = w2t + (size_t)e * HID * OUTD;
        R = HID; C = OUTD;
    }
    const int r0 = ry * 256, c0 = cx * 64;
    const int tx = threadIdx.x & 15;
    const int ta = threadIdx.x >> 4;
#pragma unroll
    for (int p = 0; p < 4; ++p) {
        int r = 2 * ta + 64 * p;
        float4 va = *(const float4*)&src[(size_t)(r0 + r)     * C + c0 + tx * 4];
        float4 vb = *(const float4*)&src[(size_t)(r0 + r + 1) * C + c0 + tx * 4];
#pragma unroll
        for (int j = 0; j < 4; ++j)
            *(uint32_t*)&tT[tx * 4 + j][r] = pk2((&va.x)[j], (&vb.x)[j]);
    }
    __syncthreads();
    const int w = threadIdx.x >> 6, l = threadIdx.x & 63;
    const int ccb = w * 2 + (l >> 5);
    const int rb  = (l & 31) * 8;
#pragma unroll
    for (int q = 0; q < 4; ++q) {
        int cc = q * 16 + ccb;
        bf16x8 o = *(const bf16x8*)&tT[cc][rb];
        *(bf16x8*)&dst[(size_t)(c0 + cc) * R + r0 + rb] = o;
    }
}

// ====== grouped GEMM, 256x256 tile, BK=32, 8 waves (2M x 4N), per-wave 128x64 ======
// R16's proven kernel + XCD-interleaved tile table (tab[blockIdx.x]; -1 -> exit):
// same-(blockIdx&7) blocks (same XCD) walk one contiguous panel-sharing range.
template <int MODE>
__global__ __launch_bounds__(512, 2)
void k_gemm(const bf16_t* __restrict__ A,    // MODE0: xb [N][DIM]; MODE1: hbuf [SLOTS][HID]
            const bf16_t* __restrict__ Bt,   // MODE0: w1t [E][HID][DIM]; MODE1: w2t [E][OUTD][HID]
            const float* __restrict__ bias,
            const int* __restrict__ tok_ids,
            const int* __restrict__ bases,
            const int* __restrict__ counts,
            const int* __restrict__ tab,     // XCD-interleaved tile table
            bf16_t* __restrict__ Y) {
    constexpr int KD   = (MODE == 0) ? DIM : HID;
    constexpr int ND   = (MODE == 0) ? HID : OUTD;
    constexpr int KLEN = (MODE == 0) ? DIM : (HID / 2);   // 1024 / 2048
    constexpr int KT   = KLEN / 32;                       // 32 / 64
    constexpr int BUFE = 16384;               // A 8192 + B 8192 elems (32 KiB)

    const int ent = tab[blockIdx.x];
    if (ent < 0) return;
    const int e     = ent >> 16;
    const int kslot = (ent >> 12) & 15;       // 0 for MODE0
    const int panel = (ent >> 8) & 15;
    const int y     = ent & 255;
    const int ne = counts[e];
    const int b0 = bases[e];
    const int m0 = y * 256, n0 = panel * 256;
    const int koff = (MODE == 0) ? 0 : kslot * KLEN;
    bf16_t* __restrict__ Yw = (MODE == 0) ? Y : (Y + (size_t)kslot * SLOTS * OUTD);

    extern __shared__ bf16_t lds[];           // 3 * BUFE elems = 96 KiB

    const int t = threadIdx.x, w = t >> 6, L = t & 63;
    const int wm = w >> 2, wn = w & 3;        // 2M x 4N; per-wave out 128x64
    const int lr = L & 15, lq = L >> 4;
    const int srow  = L >> 2;
    const int sslot = L & 3;

    int offA[8], offB[4];
#pragma unroll
    for (int i = 0; i < 8; ++i) {
        int r = wm * 128 + i * 16 + lr;
        offA[i] = r * 32 + ((lq ^ ((r >> 1) & 3)) << 3);
    }
#pragma unroll
    for (int j = 0; j < 4; ++j) {
        int r = wn * 64 + j * 16 + lr;
        offB[j] = 8192 + r * 32 + ((lq ^ ((r >> 1) & 3)) << 3);
    }
    int sdstA[2], sdstB[2];
#pragma unroll
    for (int g = 0; g < 2; ++g) {
        sdstA[g] = (g * 128 + w * 16) * 32;
        sdstB[g] = 8192 + (g * 128 + w * 16) * 32;
    }

#define GLL(srcp, dste) __builtin_amdgcn_global_load_lds( \
        (const __attribute__((address_space(1))) uint32_t*)(srcp), \
        (__attribute__((address_space(3))) uint32_t*)(lds + (dste)), 16, 0, 0)
#define STAGE(Tt, bsl) { \
        _Pragma("unroll") for (int g_ = 0; g_ < 2; ++g_) { \
            GLL(aptr[g_] + (Tt) * 32, (bsl) * BUFE + sdstA[g_]); \
            GLL(bptr[g_] + (Tt) * 32, (bsl) * BUFE + sdstB[g_]); } }

    const bf16_t* aptr[2];
    const bf16_t* bptr[2];
#pragma unroll
    for (int g = 0; g < 2; ++g) {
        int row = g * 128 + w * 16 + srow;
        int gk  = sslot ^ ((row >> 1) & 3);
        int mm = m0 + row;
        int rr = (mm < ne) ? mm : (ne - 1);
        size_t arow = (MODE == 0) ? (size_t)tok_ids[b0 + rr] * KD : (size_t)(b0 + rr) * KD;
        aptr[g] = A + arow + koff + gk * 8;
        bptr[g] = Bt + ((size_t)e * ND + n0 + row) * KD + koff + gk * 8;
    }

    f32x4 acc[8][4];
#pragma unroll
    for (int i = 0; i < 8; ++i)
#pragma unroll
        for (int j = 0; j < 4; ++j) acc[i][j] = (f32x4){0.f, 0.f, 0.f, 0.f};

    STAGE(0, 0); STAGE(1, 1);

    int cb = 0;
    int nb = 2;
    for (int T = 0; T < KT; ++T) {
        if (T < KT - 1) { asm volatile("s_waitcnt vmcnt(4)" ::: "memory"); }
        else            { asm volatile("s_waitcnt vmcnt(0)" ::: "memory"); }
        __builtin_amdgcn_s_barrier();
        if (T + 2 < KT) STAGE(T + 2, nb);

        bf16x8 fb[4], fa[8];
#pragma unroll
        for (int j = 0; j < 4; ++j) fb[j] = *(const bf16x8*)(lds + cb * BUFE + offB[j]);
#pragma unroll
        for (int i = 0; i < 4; ++i) fa[i] = *(const bf16x8*)(lds + cb * BUFE + offA[i]);
        __builtin_amdgcn_sched_barrier(0);
#pragma unroll
        for (int i = 4; i < 8; ++i) fa[i] = *(const bf16x8*)(lds + cb * BUFE + offA[i]);
        __builtin_amdgcn_sched_barrier(0);
        asm volatile("s_waitcnt lgkmcnt(4)" ::: "memory");   // fb + fa0-3 done
        __builtin_amdgcn_sched_barrier(0);
        __builtin_amdgcn_s_setprio(1);
#pragma unroll
        for (int i = 0; i < 4; ++i)
#pragma unroll
            for (int j = 0; j < 4; ++j)
                acc[i][j] = __builtin_amdgcn_mfma_f32_16x16x32_bf16(fb[j], fa[i], acc[i][j], 0, 0, 0);
        __builtin_amdgcn_s_setprio(0);
        asm volatile("s_waitcnt lgkmcnt(0)" ::: "memory");   // fa4-7 done (hidden under mh0)
        __builtin_amdgcn_sched_barrier(0);
        __builtin_amdgcn_s_setprio(1);
#pragma unroll
        for (int i = 4; i < 8; ++i)
#pragma unroll
            for (int j = 0; j < 4; ++j)
                acc[i][j] = __builtin_amdgcn_mfma_f32_16x16x32_bf16(fb[j], fa[i], acc[i][j], 0, 0, 0);
        __builtin_amdgcn_s_setprio(0);

        cb = (cb == 2) ? 0 : cb + 1;
        nb = (nb == 2) ? 0 : nb + 1;
    }

    // ---------------- epilogue: bf16 store ----------------
    const int kbias = (MODE == 0) ? 1 : (kslot == 0 ? 1 : 0);
#pragma unroll
    for (int i = 0; i < 8; ++i) {
        int gm = m0 + wm * 128 + i * 16 + lr;
        if (gm < ne) {
#pragma unroll
            for (int j = 0; j < 4; ++j) {
                int gn = n0 + wn * 64 + j * 16 + lq * 4;
                f32x4 bv = *(const f32x4*)&bias[(size_t)e * ND + gn];
                bf16x4 hv;
#pragma unroll
                for (int r = 0; r < 4; ++r) {
                    float v = acc[i][j][r];
                    if (kbias) v += bv[r];
                    if (MODE == 0) v = fmaxf(v, 0.f);
                    hv[r] = (__bf16)v;
                }
                *(bf16x4*)&Yw[(size_t)(b0 + gm) * ND + gn] = hv;
            }
        }
    }
#undef STAGE
#undef GLL
}

// ---------------- combine: out[n] = g0*(y0a+y0b) + g1*(y1a+y1b) (fp32) ----------------
__global__ void k_combine(const bf16_t* __restrict__ ybuf,   // [2][SLOTS][OUTD]
                          const int* __restrict__ slotmap,
                          const float* __restrict__ tkg,
                          float* __restrict__ out) {
    int n = blockIdx.x;
    int d = threadIdx.x * 4;
    int s0 = slotmap[2 * n], s1 = slotmap[2 * n + 1];
    float g0 = tkg[2 * n],  g1 = tkg[2 * n + 1];
    const bf16_t* y2 = ybuf + (size_t)SLOTS * OUTD;
    bf16x4 a0 = *(const bf16x4*)&ybuf[(size_t)s0 * OUTD + d];
    bf16x4 a1 = *(const bf16x4*)&y2  [(size_t)s0 * OUTD + d];
    bf16x4 c0 = *(const bf16x4*)&ybuf[(size_t)s1 * OUTD + d];
    bf16x4 c1 = *(const bf16x4*)&y2  [(size_t)s1 * OUTD + d];
    f32x4 o;
#pragma unroll
    for (int r = 0; r < 4; ++r)
        o[r] = g0 * ((float)a0[r] + (float)a1[r]) + g1 * ((float)c0[r] + (float)c1[r]);
    *(f32x4*)&out[(size_t)n * OUTD + d] = o;
}

extern "C" void kernel_launch(void* const* d_in, const int* in_sizes, int n_in,
                              void* d_out, int out_size, void* d_ws, size_t ws_size,
                              hipStream_t stream) {
    const float* x  = (const float*)d_in[0];
    const float* wg = (const float*)d_in[1];
    const float* w1 = (const float*)d_in[2];
    const float* b1 = (const float*)d_in[3];
    const float* w2 = (const float*)d_in[4];
    const float* b2 = (const float*)d_in[5];
    float* out = (float*)d_out;

    char* ws = (char*)d_ws;
    size_t o = 0;
    auto alloc = [&](size_t b) { size_t r = o; o = (o + b + 255) & ~(size_t)255; return r; };
    int*    counts  = (int*)(ws + alloc(NE * 4));
    int*    bases   = (int*)(ws + alloc(NE * 4));
    int*    tab0    = (int*)(ws + alloc(MAXT0 * 4));
    int*    tab1    = (int*)(ws + alloc(MAXT1 * 4));
    int*    tki     = (int*)(ws + alloc(SLOTS * 4));
    float*  tkg     = (float*)(ws + alloc(SLOTS * 4));
    int*    tok_ids = (int*)(ws + alloc(SLOTS * 4));
    int*    slotmap = (int*)(ws + alloc(SLOTS * 4));
    bf16_t* xb      = (bf16_t*)(ws + alloc((size_t)N_TOK * DIM * 2));
    size_t  w1t_off = alloc((size_t)NE * HID * DIM * 2);
    bf16_t* w1t     = (bf16_t*)(ws + w1t_off);
    bf16_t* ybuf    = (bf16_t*)(ws + w1t_off);   // [2][SLOTS][OUTD] aliases w1t (dead after GEMM-1)
    bf16_t* w2t     = (bf16_t*)(ws + alloc((size_t)NE * OUTD * HID * 2));
    bf16_t* hbuf    = (bf16_t*)(ws + alloc((size_t)SLOTS * HID * 2));
    (void)ws_size; (void)n_in; (void)in_sizes;

    hipFuncSetAttribute((const void*)&k_gemm<0>, hipFuncAttributeMaxDynamicSharedMemorySize, 98304);
    hipFuncSetAttribute((const void*)&k_gemm<1>, hipFuncAttributeMaxDynamicSharedMemorySize, 98304);

    // deterministic pipeline, no atomics, no ws memset needed
    k_gating<<<N_TOK / 8, 512, 0, stream>>>(x, wg, xb, tki, tkg);
    k_route<<<NE, 256, 0, stream>>>(tki, tkg, counts, bases, tab0, tab1,
                                    out + (size_t)N_TOK * OUTD, tok_ids, slotmap);
    k_transpose<<<4096, 512, 0, stream>>>(w1, w2, w1t, w2t);

    // flat grid, one tile per block; tab entry -1 -> exit
    k_gemm<0><<<MAXT0, 512, 98304, stream>>>(xb, w1t, b1, tok_ids, bases, counts, tab0, hbuf);
    k_gemm<1><<<MAXT1, 512, 98304, stream>>>(hbuf, w2t, b2, tok_ids, bases, counts, tab1, ybuf);

    k_combine<<<N_TOK, 256, 0, stream>>>(ybuf, slotmap, tkg, out);
}

// Round 21
// 336.680 us; speedup vs baseline: 2.3201x; 1.0854x over previous
//
#include <hip/hip_runtime.h>
#include <hip/hip_bf16.h>
#include <stdint.h>

#define N_TOK 4096
#define DIM   1024
#define NE    8
#define HID   4096
#define OUTD  1024
#define TOPK  2
#define SLOTS (N_TOK*TOPK)
#define MAXT0 640   // 16 * max sum(nty)
#define MAXT1 320   // 8 * max sum(nty)

typedef __bf16 bf16_t;
typedef __attribute__((ext_vector_type(8))) __bf16 bf16x8;
typedef __attribute__((ext_vector_type(4))) __bf16 bf16x4;
typedef __attribute__((ext_vector_type(4))) float  f32x4;

static __device__ __forceinline__ uint32_t pk2(float a, float b) {
    __bf16 x = (__bf16)a, y = (__bf16)b;
    return (uint32_t)__builtin_bit_cast(uint16_t, x) |
          ((uint32_t)__builtin_bit_cast(uint16_t, y) << 16);
}

// ========== fused prep: w1 transpose | w2 transpose | gating+cast (atomic-free) ==========
// 4096 transpose blocks (R15 geometry) + 512 gating blocks in ONE launch: gating's
// fp64-VALU work co-schedules under the transpose's memory stalls.
__global__ __launch_bounds__(512)
void k_prep(const float* __restrict__ x,  const float* __restrict__ wg,
            const float* __restrict__ w1, const float* __restrict__ w2,
            bf16_t* __restrict__ xb, bf16_t* __restrict__ w1t, bf16_t* __restrict__ w2t,
            int* __restrict__ tki, float* __restrict__ tkg) {
    __shared__ bf16_t tT[64][264];        // 33.8 KB
    const int bx = blockIdx.x;
    if (bx < 4096) {
        const float* src; bf16_t* dst; int R, C, ry, cx;
        if (bx < 2048) {                  // w1: [8][1024][4096] -> [8][4096][1024]
            int e = bx >> 8, rem = bx & 255;
            ry = rem >> 6; cx = rem & 63;
            src = w1 + (size_t)e * DIM * HID; dst = w1t + (size_t)e * DIM * HID;
            R = DIM; C = HID;
        } else {                          // w2: [8][4096][1024] -> [8][1024][4096]
            int b2 = bx - 2048;
            int e = b2 >> 8, rem = b2 & 255;
            ry = rem >> 4; cx = rem & 15;
            src = w2 + (size_t)e * HID * OUTD; dst = w2t + (size_t)e * HID * OUTD;
            R = HID; C = OUTD;
        }
        const int r0 = ry * 256, c0 = cx * 64;
        const int tx = threadIdx.x & 15;
        const int ta = threadIdx.x >> 4;
#pragma unroll
        for (int p = 0; p < 4; ++p) {
            int r = 2 * ta + 64 * p;
            float4 va = *(const float4*)&src[(size_t)(r0 + r)     * C + c0 + tx * 4];
            float4 vb = *(const float4*)&src[(size_t)(r0 + r + 1) * C + c0 + tx * 4];
#pragma unroll
            for (int j = 0; j < 4; ++j)
                *(uint32_t*)&tT[tx * 4 + j][r] = pk2((&va.x)[j], (&vb.x)[j]);
        }
        __syncthreads();
        const int w = threadIdx.x >> 6, l = threadIdx.x & 63;
        const int ccb = w * 2 + (l >> 5);
        const int rb  = (l & 31) * 8;
#pragma unroll
        for (int q = 0; q < 4; ++q) {
            int cc = q * 16 + ccb;
            bf16x8 o = *(const bf16x8*)&tT[cc][rb];
            *(bf16x8*)&dst[(size_t)(c0 + cc) * R + r0 + rb] = o;
        }
        return;
    }
    // gating + x-cast: 8 tokens per 512-thread block (1 wave per token)
    int n = (bx - 4096) * 8 + (threadIdx.x >> 6);
    int lane = threadIdx.x & 63;
    const float* xr = x + (size_t)n * DIM;
    double acc[NE];
#pragma unroll
    for (int e = 0; e < NE; ++e) acc[e] = 0.0;
#pragma unroll
    for (int i = 0; i < 4; ++i) {
        int d0 = i * 256 + lane * 4;
        float4 v = *(const float4*)&xr[d0];
        bf16x4 o;
        o[0] = (__bf16)v.x; o[1] = (__bf16)v.y; o[2] = (__bf16)v.z; o[3] = (__bf16)v.w;
        *(bf16x4*)&xb[(size_t)n * DIM + d0] = o;
        const float* wr = wg + (size_t)d0 * NE;
#pragma unroll
        for (int j = 0; j < 4; ++j) {
            double xv = (double)((&v.x)[j]);
#pragma unroll
            for (int e = 0; e < NE; ++e) acc[e] += xv * (double)wr[j * NE + e];
        }
    }
#pragma unroll
    for (int e = 0; e < NE; ++e)
        for (int off = 32; off > 0; off >>= 1) acc[e] += __shfl_xor(acc[e], off);
    if (lane == 0) {
        int i0 = 0; double v0 = acc[0];
#pragma unroll
        for (int e = 1; e < NE; ++e) if (acc[e] > v0) { v0 = acc[e]; i0 = e; }
        int i1 = -1; double v1 = -1e300;
#pragma unroll
        for (int e = 0; e < NE; ++e) if (e != i0 && acc[e] > v1) { v1 = acc[e]; i1 = e; }
        double e1 = exp(v1 - v0);
        double s = 1.0 + e1;
        tki[n*2]   = i0;  tki[n*2+1] = i1;
        tkg[n*2]   = (float)(1.0 / s);
        tkg[n*2+1] = (float)(e1 / s);
    }
}

// ------- merged routing (R16): counts + importance + aux + bases + tile-prefix + placement -------
__global__ __launch_bounds__(256)
void k_route(const int* __restrict__ tki, const float* __restrict__ tkg,
             int* __restrict__ counts, int* __restrict__ bases,
             int* __restrict__ tb0, int* __restrict__ tb1,
             float* __restrict__ aux_out,
             int* __restrict__ tok_ids, int* __restrict__ slotmap) {
    const int e = blockIdx.x, t = threadIdx.x;
    const int wid = t >> 6, lane = t & 63;
    int   lc[NE]; float lg[NE];
#pragma unroll
    for (int k = 0; k < NE; ++k) { lc[k] = 0; lg[k] = 0.f; }
    for (int i = t; i < SLOTS; i += 256) {
        int ee = tki[i]; float gg = tkg[i];
#pragma unroll
        for (int k = 0; k < NE; ++k) if (ee == k) { lc[k]++; lg[k] += gg; }
    }
#pragma unroll
    for (int k = 0; k < NE; ++k)
        for (int off = 32; off > 0; off >>= 1) {
            lc[k] += __shfl_xor(lc[k], off);
            lg[k] += __shfl_xor(lg[k], off);
        }
    __shared__ int   wcI[4][NE];
    __shared__ float wcF[4][NE];
    if (lane == 0)
#pragma unroll
        for (int k = 0; k < NE; ++k) { wcI[wid][k] = lc[k]; wcF[wid][k] = lg[k]; }
    __syncthreads();
    int cnt[NE];
#pragma unroll
    for (int k = 0; k < NE; ++k)
        cnt[k] = wcI[0][k] + wcI[1][k] + wcI[2][k] + wcI[3][k];
    if (e == 0 && t == 0) {
        float gs[NE];
#pragma unroll
        for (int k = 0; k < NE; ++k)
            gs[k] = wcF[0][k] + wcF[1][k] + wcF[2][k] + wcF[3][k];
        float m = 0.f;
        for (int k = 0; k < NE; ++k) m += gs[k];
        m /= (float)NE;
        float var = 0.f;
        for (int k = 0; k < NE; ++k) { float d = gs[k] - m; var += d * d; }
        var /= (float)NE;
        aux_out[0] = 0.01f * var / (m * m + 1e-10f);
        int b = 0, c0 = 0, c1 = 0;
        tb0[0] = 0; tb1[0] = 0;
        for (int k = 0; k < NE; ++k) {
            counts[k] = cnt[k]; bases[k] = b; b += cnt[k];
            int nty = (cnt[k] + 255) >> 8;
            c0 += 16 * nty; c1 += 8 * nty;
            tb0[k+1] = c0; tb1[k+1] = c1;
        }
    }
    // placement for expert e (ballot prefix-scan, deterministic)
    int run = 0;
    for (int k = 0; k < e; ++k) run += cnt[k];
    __shared__ int wc[4];
    for (int base = 0; base < SLOTS; base += 256) {
        int i = base + t;
        bool f = (tki[i] == e);
        unsigned long long bl = __ballot(f);
        int pre = __popcll(bl & ((1ull << lane) - 1ull));
        if (lane == 0) wc[wid] = __popcll(bl);
        __syncthreads();
        int woff = 0;
#pragma unroll
        for (int u = 0; u < 4; ++u) if (u < wid) woff += wc[u];
        int tot = wc[0] + wc[1] + wc[2] + wc[3];
        if (f) { int s = run + woff + pre; tok_ids[s] = i >> 1; slotmap[i] = s; }
        run += tot;
        __syncthreads();
    }
}

// ====== grouped GEMM (R16 verbatim): 256x256 tile, BK=32, 8 waves, per-wave 128x64 ======
// Flat worklist, one tile per block, tb[] prefix decode; counted-vmcnt 3-buffer read-ahead.
template <int MODE>
__global__ __launch_bounds__(512, 2)
void k_gemm(const bf16_t* __restrict__ A,    // MODE0: xb [N][DIM]; MODE1: hbuf [SLOTS][HID]
            const bf16_t* __restrict__ Bt,   // MODE0: w1t [E][HID][DIM]; MODE1: w2t [E][OUTD][HID]
            const float* __restrict__ bias,
            const int* __restrict__ tok_ids,
            const int* __restrict__ bases,
            const int* __restrict__ counts,
            const int* __restrict__ tb,      // [NE+1] tile prefix for this mode
            bf16_t* __restrict__ Y) {
    constexpr int KD   = (MODE == 0) ? DIM : HID;
    constexpr int ND   = (MODE == 0) ? HID : OUTD;
    constexpr int KLEN = (MODE == 0) ? DIM : (HID / 2);   // 1024 / 2048
    constexpr int KT   = KLEN / 32;                       // 32 / 64
    constexpr int BUFE = 16384;               // A 8192 + B 8192 elems (32 KiB)

    const int ti = blockIdx.x;
    if (ti >= tb[NE]) return;
    int e = 0;
#pragma unroll
    for (int k = 1; k < NE; ++k) if (ti >= tb[k]) e = k;
    const int local = ti - tb[e];
    const int ne = counts[e];
    const int b0 = bases[e];
    int panel, y, kslot = 0;
    if (MODE == 0) { y = local >> 4; panel = local & 15; }
    else           { y = local >> 3; int q = local & 7; panel = q >> 1; kslot = q & 1; }
    const int m0 = y * 256, n0 = panel * 256;
    const int koff = (MODE == 0) ? 0 : kslot * KLEN;
    bf16_t* __restrict__ Yw = (MODE == 0) ? Y : (Y + (size_t)kslot * SLOTS * OUTD);

    extern __shared__ bf16_t lds[];           // 3 * BUFE elems = 96 KiB

    const int t = threadIdx.x, w = t >> 6, L = t & 63;
    const int wm = w >> 2, wn = w & 3;        // 2M x 4N; per-wave out 128x64
    const int lr = L & 15, lq = L >> 4;
    const int srow  = L >> 2;
    const int sslot = L & 3;

    int offA[8], offB[4];
#pragma unroll
    for (int i = 0; i < 8; ++i) {
        int r = wm * 128 + i * 16 + lr;
        offA[i] = r * 32 + ((lq ^ ((r >> 1) & 3)) << 3);
    }
#pragma unroll
    for (int j = 0; j < 4; ++j) {
        int r = wn * 64 + j * 16 + lr;
        offB[j] = 8192 + r * 32 + ((lq ^ ((r >> 1) & 3)) << 3);
    }
    int sdstA[2], sdstB[2];
#pragma unroll
    for (int g = 0; g < 2; ++g) {
        sdstA[g] = (g * 128 + w * 16) * 32;
        sdstB[g] = 8192 + (g * 128 + w * 16) * 32;
    }

#define GLL(srcp, dste) __builtin_amdgcn_global_load_lds( \
        (const __attribute__((address_space(1))) uint32_t*)(srcp), \
        (__attribute__((address_space(3))) uint32_t*)(lds + (dste)), 16, 0, 0)
#define STAGE(Tt, bsl) { \
        _Pragma("unroll") for (int g_ = 0; g_ < 2; ++g_) { \
            GLL(aptr[g_] + (Tt) * 32, (bsl) * BUFE + sdstA[g_]); \
            GLL(bptr[g_] + (Tt) * 32, (bsl) * BUFE + sdstB[g_]); } }

    const bf16_t* aptr[2];
    const bf16_t* bptr[2];
#pragma unroll
    for (int g = 0; g < 2; ++g) {
        int row = g * 128 + w * 16 + srow;
        int gk  = sslot ^ ((row >> 1) & 3);
        int mm = m0 + row;
        int rr = (mm < ne) ? mm : (ne - 1);
        size_t arow = (MODE == 0) ? (size_t)tok_ids[b0 + rr] * KD : (size_t)(b0 + rr) * KD;
        aptr[g] = A + arow + koff + gk * 8;
        bptr[g] = Bt + ((size_t)e * ND + n0 + row) * KD + koff + gk * 8;
    }

    f32x4 acc[8][4];
#pragma unroll
    for (int i = 0; i < 8; ++i)
#pragma unroll
        for (int j = 0; j < 4; ++j) acc[i][j] = (f32x4){0.f, 0.f, 0.f, 0.f};

    STAGE(0, 0); STAGE(1, 1);

    int cb = 0;
    int nb = 2;
    for (int T = 0; T < KT; ++T) {
        if (T < KT - 1) { asm volatile("s_waitcnt vmcnt(4)" ::: "memory"); }
        else            { asm volatile("s_waitcnt vmcnt(0)" ::: "memory"); }
        __builtin_amdgcn_s_barrier();
        if (T + 2 < KT) STAGE(T + 2, nb);

        bf16x8 fb[4], fa[8];
#pragma unroll
        for (int j = 0; j < 4; ++j) fb[j] = *(const bf16x8*)(lds + cb * BUFE + offB[j]);
#pragma unroll
        for (int i = 0; i < 4; ++i) fa[i] = *(const bf16x8*)(lds + cb * BUFE + offA[i]);
        __builtin_amdgcn_sched_barrier(0);
#pragma unroll
        for (int i = 4; i < 8; ++i) fa[i] = *(const bf16x8*)(lds + cb * BUFE + offA[i]);
        __builtin_amdgcn_sched_barrier(0);
        asm volatile("s_waitcnt lgkmcnt(4)" ::: "memory");   // fb + fa0-3 done
        __builtin_amdgcn_sched_barrier(0);
        __builtin_amdgcn_s_setprio(1);
#pragma unroll
        for (int i = 0; i < 4; ++i)
#pragma unroll
            for (int j = 0; j < 4; ++j)
                acc[i][j] = __builtin_amdgcn_mfma_f32_16x16x32_bf16(fb[j], fa[i], acc[i][j], 0, 0, 0);
        __builtin_amdgcn_s_setprio(0);
        asm volatile("s_waitcnt lgkmcnt(0)" ::: "memory");   // fa4-7 done (hidden under mh0)
        __builtin_amdgcn_sched_barrier(0);
        __builtin_amdgcn_s_setprio(1);
#pragma unroll
        for (int i = 4; i < 8; ++i)
#pragma unroll
            for (int j = 0; j < 4; ++j)
                acc[i][j] = __builtin_amdgcn_mfma_f32_16x16x32_bf16(fb[j], fa[i], acc[i][j], 0, 0, 0);
        __builtin_amdgcn_s_setprio(0);

        cb = (cb == 2) ? 0 : cb + 1;
        nb = (nb == 2) ? 0 : nb + 1;
    }

    // ---------------- epilogue: bf16 store ----------------
    const int kbias = (MODE == 0) ? 1 : (kslot == 0 ? 1 : 0);
#pragma unroll
    for (int i = 0; i < 8; ++i) {
        int gm = m0 + wm * 128 + i * 16 + lr;
        if (gm < ne) {
#pragma unroll
            for (int j = 0; j < 4; ++j) {
                int gn = n0 + wn * 64 + j * 16 + lq * 4;
                f32x4 bv = *(const f32x4*)&bias[(size_t)e * ND + gn];
                bf16x4 hv;
#pragma unroll
                for (int r = 0; r < 4; ++r) {
                    float v = acc[i][j][r];
                    if (kbias) v += bv[r];
                    if (MODE == 0) v = fmaxf(v, 0.f);
                    hv[r] = (__bf16)v;
                }
                *(bf16x4*)&Yw[(size_t)(b0 + gm) * ND + gn] = hv;
            }
        }
    }
#undef STAGE
#undef GLL
}

// ---------------- combine: out[n] = g0*(y0a+y0b) + g1*(y1a+y1b) (fp32) ----------------
__global__ void k_combine(const bf16_t* __restrict__ ybuf,   // [2][SLOTS][OUTD]
                          const int* __restrict__ slotmap,
                          const float* __restrict__ tkg,
                          float* __restrict__ out) {
    int n = blockIdx.x;
    int d = threadIdx.x * 4;
    int s0 = slotmap[2 * n], s1 = slotmap[2 * n + 1];
    float g0 = tkg[2 * n],  g1 = tkg[2 * n + 1];
    const bf16_t* y2 = ybuf + (size_t)SLOTS * OUTD;
    bf16x4 a0 = *(const bf16x4*)&ybuf[(size_t)s0 * OUTD + d];
    bf16x4 a1 = *(const bf16x4*)&y2  [(size_t)s0 * OUTD + d];
    bf16x4 c0 = *(const bf16x4*)&ybuf[(size_t)s1 * OUTD + d];
    bf16x4 c1 = *(const bf16x4*)&y2  [(size_t)s1 * OUTD + d];
    f32x4 o;
#pragma unroll
    for (int r = 0; r < 4; ++r)
        o[r] = g0 * ((float)a0[r] + (float)a1[r]) + g1 * ((float)c0[r] + (float)c1[r]);
    *(f32x4*)&out[(size_t)n * OUTD + d] = o;
}

extern "C" void kernel_launch(void* const* d_in, const int* in_sizes, int n_in,
                              void* d_out, int out_size, void* d_ws, size_t ws_size,
                              hipStream_t stream) {
    const float* x  = (const float*)d_in[0];
    const float* wg = (const float*)d_in[1];
    const float* w1 = (const float*)d_in[2];
    const float* b1 = (const float*)d_in[3];
    const float* w2 = (const float*)d_in[4];
    const float* b2 = (const float*)d_in[5];
    float* out = (float*)d_out;

    char* ws = (char*)d_ws;
    size_t o = 0;
    auto alloc = [&](size_t b) { size_t r = o; o = (o + b + 255) & ~(size_t)255; return r; };
    int*    counts  = (int*)(ws + alloc(NE * 4));
    int*    bases   = (int*)(ws + alloc(NE * 4));
    int*    tb0     = (int*)(ws + alloc((NE + 1) * 4));
    int*    tb1     = (int*)(ws + alloc((NE + 1) * 4));
    int*    tki     = (int*)(ws + alloc(SLOTS * 4));
    float*  tkg     = (float*)(ws + alloc(SLOTS * 4));
    int*    tok_ids = (int*)(ws + alloc(SLOTS * 4));
    int*    slotmap = (int*)(ws + alloc(SLOTS * 4));
    bf16_t* xb      = (bf16_t*)(ws + alloc((size_t)N_TOK * DIM * 2));
    size_t  w1t_off = alloc((size_t)NE * HID * DIM * 2);
    bf16_t* w1t     = (bf16_t*)(ws + w1t_off);
    bf16_t* ybuf    = (bf16_t*)(ws + w1t_off);   // [2][SLOTS][OUTD] aliases w1t (dead after GEMM-1)
    bf16_t* w2t     = (bf16_t*)(ws + alloc((size_t)NE * OUTD * HID * 2));
    bf16_t* hbuf    = (bf16_t*)(ws + alloc((size_t)SLOTS * HID * 2));
    (void)ws_size; (void)n_in; (void)in_sizes;

    hipFuncSetAttribute((const void*)&k_gemm<0>, hipFuncAttributeMaxDynamicSharedMemorySize, 98304);
    hipFuncSetAttribute((const void*)&k_gemm<1>, hipFuncAttributeMaxDynamicSharedMemorySize, 98304);

    // fused prep: 4096 transpose blocks + 512 gating blocks, one launch, no atomics
    k_prep<<<4096 + 512, 512, 0, stream>>>(x, wg, w1, w2, xb, w1t, w2t, tki, tkg);
    k_route<<<NE, 256, 0, stream>>>(tki, tkg, counts, bases, tb0, tb1,
                                    out + (size_t)N_TOK * OUTD, tok_ids, slotmap);

    // flat worklist: one tile per block; excess blocks exit on tb[NE]
    k_gemm<0><<<MAXT0, 512, 98304, stream>>>(xb, w1t, b1, tok_ids, bases, counts, tb0, hbuf);
    k_gemm<1><<<MAXT1, 512, 98304, stream>>>(hbuf, w2t, b2, tok_ids, bases, counts, tb1, ybuf);

    k_combine<<<N_TOK, 256, 0, stream>>>(ybuf, slotmap, tkg, out);
}

// Round 22
// 334.366 us; speedup vs baseline: 2.3361x; 1.0069x over previous
//
#include <hip/hip_runtime.h>
#include <hip/hip_bf16.h>
#include <stdint.h>

#define N_TOK 4096
#define DIM   1024
#define NE    8
#define HID   4096
#define OUTD  1024
#define TOPK  2
#define SLOTS (N_TOK*TOPK)
#define MAXT0 640   // 16 * max sum(nty)
#define MAXT1 320   // 8 * max sum(nty)

typedef __bf16 bf16_t;
typedef __attribute__((ext_vector_type(8))) __bf16 bf16x8;
typedef __attribute__((ext_vector_type(4))) __bf16 bf16x4;
typedef __attribute__((ext_vector_type(4))) float  f32x4;

// ========== fused prep: w1 transpose | w2 transpose | gating+cast (atomic-free) ==========
// R23 transpose v4: 256(src rows) x 128(src cols) tiles, 512 thr.
//  - read: thread (tx=t&31, ro=t>>5) loads 8 float4 from rows rblk..rblk+7, cols 4tx..+3
//    -> per wave-instr 2 full 512B row segments (was 4x256B).
//  - pack: per col j, bf16x8 of the 8 rows -> ONE ds_write_b128 to tT[4tx+j][rblk]
//    -> write banks spread ~16 (~2-way) vs R21's 8-way dword scatter (7.3M conflicts).
//  - write-out: contiguous b128 reads (conflict-free), 2 x 512B global segments/instr.
// LDS 128x264x2 = 67.6 KB -> 2 blocks/CU. 2048 transpose blocks + 512 gating blocks.
__global__ __launch_bounds__(512)
void k_prep(const float* __restrict__ x,  const float* __restrict__ wg,
            const float* __restrict__ w1, const float* __restrict__ w2,
            bf16_t* __restrict__ xb, bf16_t* __restrict__ w1t, bf16_t* __restrict__ w2t,
            int* __restrict__ tki, float* __restrict__ tkg) {
    __shared__ bf16_t tT[128][264];       // 67.6 KB
    const int bx = blockIdx.x;
    const int t  = threadIdx.x;
    if (bx < 2048) {
        const float* src; bf16_t* dst; int R, C, ry, cx;
        if (bx < 1024) {                  // w1: [8][1024][4096] -> [8][4096][1024]
            int e = bx >> 7, rem = bx & 127;
            ry = rem >> 5; cx = rem & 31;
            src = w1 + (size_t)e * DIM * HID; dst = w1t + (size_t)e * DIM * HID;
            R = DIM; C = HID;
        } else {                          // w2: [8][4096][1024] -> [8][1024][4096]
            int b2 = bx - 1024;
            int e = b2 >> 7, rem = b2 & 127;
            ry = rem >> 3; cx = rem & 7;
            src = w2 + (size_t)e * HID * OUTD; dst = w2t + (size_t)e * HID * OUTD;
            R = HID; C = OUTD;
        }
        const int r0 = ry * 256, c0 = cx * 128;
        const int tx = t & 31;            // col-quad: cols c0 + 4tx .. +3
        const int ro = t >> 5;            // row-octet 0..15
#pragma unroll
        for (int p = 0; p < 2; ++p) {
            int rblk = 128 * p + 8 * ro;
            float4 va[8];
#pragma unroll
            for (int u = 0; u < 8; ++u)
                va[u] = *(const float4*)&src[(size_t)(r0 + rblk + u) * C + c0 + tx * 4];
#pragma unroll
            for (int j = 0; j < 4; ++j) {
                bf16x8 o;
#pragma unroll
                for (int u = 0; u < 8; ++u) o[u] = (__bf16)((&va[u].x)[j]);
                *(bf16x8*)&tT[tx * 4 + j][rblk] = o;
            }
        }
        __syncthreads();
        const int w = t >> 6, l = t & 63;
        const int ccb = w * 2 + (l >> 5);     // 0..15
        const int rb  = (l & 31) * 8;         // 0..248
#pragma unroll
        for (int q = 0; q < 8; ++q) {
            int cc = q * 16 + ccb;
            bf16x8 o = *(const bf16x8*)&tT[cc][rb];
            *(bf16x8*)&dst[(size_t)(c0 + cc) * R + r0 + rb] = o;
        }
        return;
    }
    // gating + x-cast: 8 tokens per 512-thread block (1 wave per token)
    int n = (bx - 2048) * 8 + (t >> 6);
    int lane = t & 63;
    const float* xr = x + (size_t)n * DIM;
    double acc[NE];
#pragma unroll
    for (int e = 0; e < NE; ++e) acc[e] = 0.0;
#pragma unroll
    for (int i = 0; i < 4; ++i) {
        int d0 = i * 256 + lane * 4;
        float4 v = *(const float4*)&xr[d0];
        bf16x4 o;
        o[0] = (__bf16)v.x; o[1] = (__bf16)v.y; o[2] = (__bf16)v.z; o[3] = (__bf16)v.w;
        *(bf16x4*)&xb[(size_t)n * DIM + d0] = o;
        const float* wr = wg + (size_t)d0 * NE;
#pragma unroll
        for (int j = 0; j < 4; ++j) {
            double xv = (double)((&v.x)[j]);
#pragma unroll
            for (int e = 0; e < NE; ++e) acc[e] += xv * (double)wr[j * NE + e];
        }
    }
#pragma unroll
    for (int e = 0; e < NE; ++e)
        for (int off = 32; off > 0; off >>= 1) acc[e] += __shfl_xor(acc[e], off);
    if (lane == 0) {
        int i0 = 0; double v0 = acc[0];
#pragma unroll
        for (int e = 1; e < NE; ++e) if (acc[e] > v0) { v0 = acc[e]; i0 = e; }
        int i1 = -1; double v1 = -1e300;
#pragma unroll
        for (int e = 0; e < NE; ++e) if (e != i0 && acc[e] > v1) { v1 = acc[e]; i1 = e; }
        double e1 = exp(v1 - v0);
        double s = 1.0 + e1;
        tki[n*2]   = i0;  tki[n*2+1] = i1;
        tkg[n*2]   = (float)(1.0 / s);
        tkg[n*2+1] = (float)(e1 / s);
    }
}

// ------- merged routing (R16): counts + importance + aux + bases + tile-prefix + placement -------
__global__ __launch_bounds__(256)
void k_route(const int* __restrict__ tki, const float* __restrict__ tkg,
             int* __restrict__ counts, int* __restrict__ bases,
             int* __restrict__ tb0, int* __restrict__ tb1,
             float* __restrict__ aux_out,
             int* __restrict__ tok_ids, int* __restrict__ slotmap) {
    const int e = blockIdx.x, t = threadIdx.x;
    const int wid = t >> 6, lane = t & 63;
    int   lc[NE]; float lg[NE];
#pragma unroll
    for (int k = 0; k < NE; ++k) { lc[k] = 0; lg[k] = 0.f; }
    for (int i = t; i < SLOTS; i += 256) {
        int ee = tki[i]; float gg = tkg[i];
#pragma unroll
        for (int k = 0; k < NE; ++k) if (ee == k) { lc[k]++; lg[k] += gg; }
    }
#pragma unroll
    for (int k = 0; k < NE; ++k)
        for (int off = 32; off > 0; off >>= 1) {
            lc[k] += __shfl_xor(lc[k], off);
            lg[k] += __shfl_xor(lg[k], off);
        }
    __shared__ int   wcI[4][NE];
    __shared__ float wcF[4][NE];
    if (lane == 0)
#pragma unroll
        for (int k = 0; k < NE; ++k) { wcI[wid][k] = lc[k]; wcF[wid][k] = lg[k]; }
    __syncthreads();
    int cnt[NE];
#pragma unroll
    for (int k = 0; k < NE; ++k)
        cnt[k] = wcI[0][k] + wcI[1][k] + wcI[2][k] + wcI[3][k];
    if (e == 0 && t == 0) {
        float gs[NE];
#pragma unroll
        for (int k = 0; k < NE; ++k)
            gs[k] = wcF[0][k] + wcF[1][k] + wcF[2][k] + wcF[3][k];
        float m = 0.f;
        for (int k = 0; k < NE; ++k) m += gs[k];
        m /= (float)NE;
        float var = 0.f;
        for (int k = 0; k < NE; ++k) { float d = gs[k] - m; var += d * d; }
        var /= (float)NE;
        aux_out[0] = 0.01f * var / (m * m + 1e-10f);
        int b = 0, c0 = 0, c1 = 0;
        tb0[0] = 0; tb1[0] = 0;
        for (int k = 0; k < NE; ++k) {
            counts[k] = cnt[k]; bases[k] = b; b += cnt[k];
            int nty = (cnt[k] + 255) >> 8;
            c0 += 16 * nty; c1 += 8 * nty;
            tb0[k+1] = c0; tb1[k+1] = c1;
        }
    }
    // placement for expert e (ballot prefix-scan, deterministic)
    int run = 0;
    for (int k = 0; k < e; ++k) run += cnt[k];
    __shared__ int wc[4];
    for (int base = 0; base < SLOTS; base += 256) {
        int i = base + t;
        bool f = (tki[i] == e);
        unsigned long long bl = __ballot(f);
        int pre = __popcll(bl & ((1ull << lane) - 1ull));
        if (lane == 0) wc[wid] = __popcll(bl);
        __syncthreads();
        int woff = 0;
#pragma unroll
        for (int u = 0; u < 4; ++u) if (u < wid) woff += wc[u];
        int tot = wc[0] + wc[1] + wc[2] + wc[3];
        if (f) { int s = run + woff + pre; tok_ids[s] = i >> 1; slotmap[i] = s; }
        run += tot;
        __syncthreads();
    }
}

// ====== grouped GEMM (R16 verbatim): 256x256 tile, BK=32, 8 waves, per-wave 128x64 ======
template <int MODE>
__global__ __launch_bounds__(512, 2)
void k_gemm(const bf16_t* __restrict__ A,    // MODE0: xb [N][DIM]; MODE1: hbuf [SLOTS][HID]
            const bf16_t* __restrict__ Bt,   // MODE0: w1t [E][HID][DIM]; MODE1: w2t [E][OUTD][HID]
            const float* __restrict__ bias,
            const int* __restrict__ tok_ids,
            const int* __restrict__ bases,
            const int* __restrict__ counts,
            const int* __restrict__ tb,      // [NE+1] tile prefix for this mode
            bf16_t* __restrict__ Y) {
    constexpr int KD   = (MODE == 0) ? DIM : HID;
    constexpr int ND   = (MODE == 0) ? HID : OUTD;
    constexpr int KLEN = (MODE == 0) ? DIM : (HID / 2);   // 1024 / 2048
    constexpr int KT   = KLEN / 32;                       // 32 / 64
    constexpr int BUFE = 16384;               // A 8192 + B 8192 elems (32 KiB)

    const int ti = blockIdx.x;
    if (ti >= tb[NE]) return;
    int e = 0;
#pragma unroll
    for (int k = 1; k < NE; ++k) if (ti >= tb[k]) e = k;
    const int local = ti - tb[e];
    const int ne = counts[e];
    const int b0 = bases[e];
    int panel, y, kslot = 0;
    if (MODE == 0) { y = local >> 4; panel = local & 15; }
    else           { y = local >> 3; int q = local & 7; panel = q >> 1; kslot = q & 1; }
    const int m0 = y * 256, n0 = panel * 256;
    const int koff = (MODE == 0) ? 0 : kslot * KLEN;
    bf16_t* __restrict__ Yw = (MODE == 0) ? Y : (Y + (size_t)kslot * SLOTS * OUTD);

    extern __shared__ bf16_t lds[];           // 3 * BUFE elems = 96 KiB

    const int t = threadIdx.x, w = t >> 6, L = t & 63;
    const int wm = w >> 2, wn = w & 3;        // 2M x 4N; per-wave out 128x64
    const int lr = L & 15, lq = L >> 4;
    const int srow  = L >> 2;
    const int sslot = L & 3;

    int offA[8], offB[4];
#pragma unroll
    for (int i = 0; i < 8; ++i) {
        int r = wm * 128 + i * 16 + lr;
        offA[i] = r * 32 + ((lq ^ ((r >> 1) & 3)) << 3);
    }
#pragma unroll
    for (int j = 0; j < 4; ++j) {
        int r = wn * 64 + j * 16 + lr;
        offB[j] = 8192 + r * 32 + ((lq ^ ((r >> 1) & 3)) << 3);
    }
    int sdstA[2], sdstB[2];
#pragma unroll
    for (int g = 0; g < 2; ++g) {
        sdstA[g] = (g * 128 + w * 16) * 32;
        sdstB[g] = 8192 + (g * 128 + w * 16) * 32;
    }

#define GLL(srcp, dste) __builtin_amdgcn_global_load_lds( \
        (const __attribute__((address_space(1))) uint32_t*)(srcp), \
        (__attribute__((address_space(3))) uint32_t*)(lds + (dste)), 16, 0, 0)
#define STAGE(Tt, bsl) { \
        _Pragma("unroll") for (int g_ = 0; g_ < 2; ++g_) { \
            GLL(aptr[g_] + (Tt) * 32, (bsl) * BUFE + sdstA[g_]); \
            GLL(bptr[g_] + (Tt) * 32, (bsl) * BUFE + sdstB[g_]); } }

    const bf16_t* aptr[2];
    const bf16_t* bptr[2];
#pragma unroll
    for (int g = 0; g < 2; ++g) {
        int row = g * 128 + w * 16 + srow;
        int gk  = sslot ^ ((row >> 1) & 3);
        int mm = m0 + row;
        int rr = (mm < ne) ? mm : (ne - 1);
        size_t arow = (MODE == 0) ? (size_t)tok_ids[b0 + rr] * KD : (size_t)(b0 + rr) * KD;
        aptr[g] = A + arow + koff + gk * 8;
        bptr[g] = Bt + ((size_t)e * ND + n0 + row) * KD + koff + gk * 8;
    }

    f32x4 acc[8][4];
#pragma unroll
    for (int i = 0; i < 8; ++i)
#pragma unroll
        for (int j = 0; j < 4; ++j) acc[i][j] = (f32x4){0.f, 0.f, 0.f, 0.f};

    STAGE(0, 0); STAGE(1, 1);

    int cb = 0;
    int nb = 2;
    for (int T = 0; T < KT; ++T) {
        if (T < KT - 1) { asm volatile("s_waitcnt vmcnt(4)" ::: "memory"); }
        else            { asm volatile("s_waitcnt vmcnt(0)" ::: "memory"); }
        __builtin_amdgcn_s_barrier();
        if (T + 2 < KT) STAGE(T + 2, nb);

        bf16x8 fb[4], fa[8];
#pragma unroll
        for (int j = 0; j < 4; ++j) fb[j] = *(const bf16x8*)(lds + cb * BUFE + offB[j]);
#pragma unroll
        for (int i = 0; i < 4; ++i) fa[i] = *(const bf16x8*)(lds + cb * BUFE + offA[i]);
        __builtin_amdgcn_sched_barrier(0);
#pragma unroll
        for (int i = 4; i < 8; ++i) fa[i] = *(const bf16x8*)(lds + cb * BUFE + offA[i]);
        __builtin_amdgcn_sched_barrier(0);
        asm volatile("s_waitcnt lgkmcnt(4)" ::: "memory");   // fb + fa0-3 done
        __builtin_amdgcn_sched_barrier(0);
        __builtin_amdgcn_s_setprio(1);
#pragma unroll
        for (int i = 0; i < 4; ++i)
#pragma unroll
            for (int j = 0; j < 4; ++j)
                acc[i][j] = __builtin_amdgcn_mfma_f32_16x16x32_bf16(fb[j], fa[i], acc[i][j], 0, 0, 0);
        __builtin_amdgcn_s_setprio(0);
        asm volatile("s_waitcnt lgkmcnt(0)" ::: "memory");   // fa4-7 done (hidden under mh0)
        __builtin_amdgcn_sched_barrier(0);
        __builtin_amdgcn_s_setprio(1);
#pragma unroll
        for (int i = 4; i < 8; ++i)
#pragma unroll
            for (int j = 0; j < 4; ++j)
                acc[i][j] = __builtin_amdgcn_mfma_f32_16x16x32_bf16(fb[j], fa[i], acc[i][j], 0, 0, 0);
        __builtin_amdgcn_s_setprio(0);

        cb = (cb == 2) ? 0 : cb + 1;
        nb = (nb == 2) ? 0 : nb + 1;
    }

    // ---------------- epilogue: bf16 store ----------------
    const int kbias = (MODE == 0) ? 1 : (kslot == 0 ? 1 : 0);
#pragma unroll
    for (int i = 0; i < 8; ++i) {
        int gm = m0 + wm * 128 + i * 16 + lr;
        if (gm < ne) {
#pragma unroll
            for (int j = 0; j < 4; ++j) {
                int gn = n0 + wn * 64 + j * 16 + lq * 4;
                f32x4 bv = *(const f32x4*)&bias[(size_t)e * ND + gn];
                bf16x4 hv;
#pragma unroll
                for (int r = 0; r < 4; ++r) {
                    float v = acc[i][j][r];
                    if (kbias) v += bv[r];
                    if (MODE == 0) v = fmaxf(v, 0.f);
                    hv[r] = (__bf16)v;
                }
                *(bf16x4*)&Yw[(size_t)(b0 + gm) * ND + gn] = hv;
            }
        }
    }
#undef STAGE
#undef GLL
}

// ---------------- combine: out[n] = g0*(y0a+y0b) + g1*(y1a+y1b) (fp32) ----------------
__global__ void k_combine(const bf16_t* __restrict__ ybuf,   // [2][SLOTS][OUTD]
                          const int* __restrict__ slotmap,
                          const float* __restrict__ tkg,
                          float* __restrict__ out) {
    int n = blockIdx.x;
    int d = threadIdx.x * 4;
    int s0 = slotmap[2 * n], s1 = slotmap[2 * n + 1];
    float g0 = tkg[2 * n],  g1 = tkg[2 * n + 1];
    const bf16_t* y2 = ybuf + (size_t)SLOTS * OUTD;
    bf16x4 a0 = *(const bf16x4*)&ybuf[(size_t)s0 * OUTD + d];
    bf16x4 a1 = *(const bf16x4*)&y2  [(size_t)s0 * OUTD + d];
    bf16x4 c0 = *(const bf16x4*)&ybuf[(size_t)s1 * OUTD + d];
    bf16x4 c1 = *(const bf16x4*)&y2  [(size_t)s1 * OUTD + d];
    f32x4 o;
#pragma unroll
    for (int r = 0; r < 4; ++r)
        o[r] = g0 * ((float)a0[r] + (float)a1[r]) + g1 * ((float)c0[r] + (float)c1[r]);
    *(f32x4*)&out[(size_t)n * OUTD + d] = o;
}

extern "C" void kernel_launch(void* const* d_in, const int* in_sizes, int n_in,
                              void* d_out, int out_size, void* d_ws, size_t ws_size,
                              hipStream_t stream) {
    const float* x  = (const float*)d_in[0];
    const float* wg = (const float*)d_in[1];
    const float* w1 = (const float*)d_in[2];
    const float* b1 = (const float*)d_in[3];
    const float* w2 = (const float*)d_in[4];
    const float* b2 = (const float*)d_in[5];
    float* out = (float*)d_out;

    char* ws = (char*)d_ws;
    size_t o = 0;
    auto alloc = [&](size_t b) { size_t r = o; o = (o + b + 255) & ~(size_t)255; return r; };
    int*    counts  = (int*)(ws + alloc(NE * 4));
    int*    bases   = (int*)(ws + alloc(NE * 4));
    int*    tb0     = (int*)(ws + alloc((NE + 1) * 4));
    int*    tb1     = (int*)(ws + alloc((NE + 1) * 4));
    int*    tki     = (int*)(ws + alloc(SLOTS * 4));
    float*  tkg     = (float*)(ws + alloc(SLOTS * 4));
    int*    tok_ids = (int*)(ws + alloc(SLOTS * 4));
    int*    slotmap = (int*)(ws + alloc(SLOTS * 4));
    bf16_t* xb      = (bf16_t*)(ws + alloc((size_t)N_TOK * DIM * 2));
    size_t  w1t_off = alloc((size_t)NE * HID * DIM * 2);
    bf16_t* w1t     = (bf16_t*)(ws + w1t_off);
    bf16_t* ybuf    = (bf16_t*)(ws + w1t_off);   // [2][SLOTS][OUTD] aliases w1t (dead after GEMM-1)
    bf16_t* w2t     = (bf16_t*)(ws + alloc((size_t)NE * OUTD * HID * 2));
    bf16_t* hbuf    = (bf16_t*)(ws + alloc((size_t)SLOTS * HID * 2));
    (void)ws_size; (void)n_in; (void)in_sizes;

    hipFuncSetAttribute((const void*)&k_gemm<0>, hipFuncAttributeMaxDynamicSharedMemorySize, 98304);
    hipFuncSetAttribute((const void*)&k_gemm<1>, hipFuncAttributeMaxDynamicSharedMemorySize, 98304);

    // fused prep: 2048 transpose blocks (256x128 tiles) + 512 gating blocks, no atomics
    k_prep<<<2048 + 512, 512, 0, stream>>>(x, wg, w1, w2, xb, w1t, w2t, tki, tkg);
    k_route<<<NE, 256, 0, stream>>>(tki, tkg, counts, bases, tb0, tb1,
                                    out + (size_t)N_TOK * OUTD, tok_ids, slotmap);

    // flat worklist: one tile per block; excess blocks exit on tb[NE]
    k_gemm<0><<<MAXT0, 512, 98304, stream>>>(xb, w1t, b1, tok_ids, bases, counts, tb0, hbuf);
    k_gemm<1><<<MAXT1, 512, 98304, stream>>>(hbuf, w2t, b2, tok_ids, bases, counts, tb1, ybuf);

    k_combine<<<N_TOK, 256, 0, stream>>>(ybuf, slotmap, tkg, out);
}

// Round 23
// 312.782 us; speedup vs baseline: 2.4973x; 1.0690x over previous
//
#include <hip/hip_runtime.h>
#include <hip/hip_bf16.h>
#include <stdint.h>

#define N_TOK 4096
#define DIM   1024
#define NE    8
#define HID   4096
#define OUTD  1024
#define TOPK  2
#define SLOTS (N_TOK*TOPK)
#define MAXT0 640   // 16 * max sum(nty)
#define MAXT1 320   // 8 * max sum(nty)
#define W2TB  1024  // w2 transpose blocks (8 experts x 16 ry x 8 cx)

typedef __bf16 bf16_t;
typedef __attribute__((ext_vector_type(8))) __bf16 bf16x8;
typedef __attribute__((ext_vector_type(4))) __bf16 bf16x4;
typedef __attribute__((ext_vector_type(4))) float  f32x4;

// ---- shared 256x128 transpose tile body (reads fp32 [R][C], writes bf16 [C][R]) ----
// read: 2 full 512B row-segments per wave-instr; LDS write: b128 (≈2-way banks);
// write-out: contiguous b128 reads + 2x512B global segments per instr.
static __device__ __forceinline__ void tr_tile(const float* __restrict__ src,
                                               bf16_t* __restrict__ dst,
                                               int R, int C, int ry, int cx,
                                               bf16_t (*tT)[264], int t) {
    const int r0 = ry * 256, c0 = cx * 128;
    const int tx = t & 31;            // col-quad: cols c0 + 4tx .. +3
    const int ro = t >> 5;            // row-octet 0..15
#pragma unroll
    for (int p = 0; p < 2; ++p) {
        int rblk = 128 * p + 8 * ro;
        float4 va[8];
#pragma unroll
        for (int u = 0; u < 8; ++u)
            va[u] = *(const float4*)&src[(size_t)(r0 + rblk + u) * C + c0 + tx * 4];
#pragma unroll
        for (int j = 0; j < 4; ++j) {
            bf16x8 o;
#pragma unroll
            for (int u = 0; u < 8; ++u) o[u] = (__bf16)((&va[u].x)[j]);
            *(bf16x8*)&tT[tx * 4 + j][rblk] = o;
        }
    }
    __syncthreads();
    const int w = t >> 6, l = t & 63;
    const int ccb = w * 2 + (l >> 5);     // 0..15
    const int rb  = (l & 31) * 8;         // 0..248
#pragma unroll
    for (int q = 0; q < 8; ++q) {
        int cc = q * 16 + ccb;
        bf16x8 o = *(const bf16x8*)&tT[cc][rb];
        *(bf16x8*)&dst[(size_t)(c0 + cc) * R + r0 + rb] = o;
    }
}

// ========== prep: w1 transpose (1024 blocks) | gating+cast (512 blocks) ==========
// R24: w2 transpose moved INTO the k_gemm<0> launch (hides under its idle BW).
__global__ __launch_bounds__(512)
void k_prep(const float* __restrict__ x,  const float* __restrict__ wg,
            const float* __restrict__ w1,
            bf16_t* __restrict__ xb, bf16_t* __restrict__ w1t,
            int* __restrict__ tki, float* __restrict__ tkg) {
    __shared__ bf16_t tT[128][264];       // 67.6 KB
    const int bx = blockIdx.x;
    const int t  = threadIdx.x;
    if (bx < 1024) {                      // w1: [8][1024][4096] -> [8][4096][1024]
        int e = bx >> 7, rem = bx & 127;
        tr_tile(w1 + (size_t)e * DIM * HID, w1t + (size_t)e * DIM * HID,
                DIM, HID, rem >> 5, rem & 31, tT, t);
        return;
    }
    // gating + x-cast: 8 tokens per 512-thread block (1 wave per token)
    int n = (bx - 1024) * 8 + (t >> 6);
    int lane = t & 63;
    const float* xr = x + (size_t)n * DIM;
    double acc[NE];
#pragma unroll
    for (int e = 0; e < NE; ++e) acc[e] = 0.0;
#pragma unroll
    for (int i = 0; i < 4; ++i) {
        int d0 = i * 256 + lane * 4;
        float4 v = *(const float4*)&xr[d0];
        bf16x4 o;
        o[0] = (__bf16)v.x; o[1] = (__bf16)v.y; o[2] = (__bf16)v.z; o[3] = (__bf16)v.w;
        *(bf16x4*)&xb[(size_t)n * DIM + d0] = o;
        const float* wr = wg + (size_t)d0 * NE;
#pragma unroll
        for (int j = 0; j < 4; ++j) {
            double xv = (double)((&v.x)[j]);
#pragma unroll
            for (int e = 0; e < NE; ++e) acc[e] += xv * (double)wr[j * NE + e];
        }
    }
#pragma unroll
    for (int e = 0; e < NE; ++e)
        for (int off = 32; off > 0; off >>= 1) acc[e] += __shfl_xor(acc[e], off);
    if (lane == 0) {
        int i0 = 0; double v0 = acc[0];
#pragma unroll
        for (int e = 1; e < NE; ++e) if (acc[e] > v0) { v0 = acc[e]; i0 = e; }
        int i1 = -1; double v1 = -1e300;
#pragma unroll
        for (int e = 0; e < NE; ++e) if (e != i0 && acc[e] > v1) { v1 = acc[e]; i1 = e; }
        double e1 = exp(v1 - v0);
        double s = 1.0 + e1;
        tki[n*2]   = i0;  tki[n*2+1] = i1;
        tkg[n*2]   = (float)(1.0 / s);
        tkg[n*2+1] = (float)(e1 / s);
    }
}

// ------- merged routing (R16): counts + importance + aux + bases + tile-prefix + placement -------
__global__ __launch_bounds__(256)
void k_route(const int* __restrict__ tki, const float* __restrict__ tkg,
             int* __restrict__ counts, int* __restrict__ bases,
             int* __restrict__ tb0, int* __restrict__ tb1,
             float* __restrict__ aux_out,
             int* __restrict__ tok_ids, int* __restrict__ slotmap) {
    const int e = blockIdx.x, t = threadIdx.x;
    const int wid = t >> 6, lane = t & 63;
    int   lc[NE]; float lg[NE];
#pragma unroll
    for (int k = 0; k < NE; ++k) { lc[k] = 0; lg[k] = 0.f; }
    for (int i = t; i < SLOTS; i += 256) {
        int ee = tki[i]; float gg = tkg[i];
#pragma unroll
        for (int k = 0; k < NE; ++k) if (ee == k) { lc[k]++; lg[k] += gg; }
    }
#pragma unroll
    for (int k = 0; k < NE; ++k)
        for (int off = 32; off > 0; off >>= 1) {
            lc[k] += __shfl_xor(lc[k], off);
            lg[k] += __shfl_xor(lg[k], off);
        }
    __shared__ int   wcI[4][NE];
    __shared__ float wcF[4][NE];
    if (lane == 0)
#pragma unroll
        for (int k = 0; k < NE; ++k) { wcI[wid][k] = lc[k]; wcF[wid][k] = lg[k]; }
    __syncthreads();
    int cnt[NE];
#pragma unroll
    for (int k = 0; k < NE; ++k)
        cnt[k] = wcI[0][k] + wcI[1][k] + wcI[2][k] + wcI[3][k];
    if (e == 0 && t == 0) {
        float gs[NE];
#pragma unroll
        for (int k = 0; k < NE; ++k)
            gs[k] = wcF[0][k] + wcF[1][k] + wcF[2][k] + wcF[3][k];
        float m = 0.f;
        for (int k = 0; k < NE; ++k) m += gs[k];
        m /= (float)NE;
        float var = 0.f;
        for (int k = 0; k < NE; ++k) { float d = gs[k] - m; var += d * d; }
        var /= (float)NE;
        aux_out[0] = 0.01f * var / (m * m + 1e-10f);
        int b = 0, c0 = 0, c1 = 0;
        tb0[0] = 0; tb1[0] = 0;
        for (int k = 0; k < NE; ++k) {
            counts[k] = cnt[k]; bases[k] = b; b += cnt[k];
            int nty = (cnt[k] + 255) >> 8;
            c0 += 16 * nty; c1 += 8 * nty;
            tb0[k+1] = c0; tb1[k+1] = c1;
        }
    }
    // placement for expert e (ballot prefix-scan, deterministic)
    int run = 0;
    for (int k = 0; k < e; ++k) run += cnt[k];
    __shared__ int wc[4];
    for (int base = 0; base < SLOTS; base += 256) {
        int i = base + t;
        bool f = (tki[i] == e);
        unsigned long long bl = __ballot(f);
        int pre = __popcll(bl & ((1ull << lane) - 1ull));
        if (lane == 0) wc[wid] = __popcll(bl);
        __syncthreads();
        int woff = 0;
#pragma unroll
        for (int u = 0; u < 4; ++u) if (u < wid) woff += wc[u];
        int tot = wc[0] + wc[1] + wc[2] + wc[3];
        if (f) { int s = run + woff + pre; tok_ids[s] = i >> 1; slotmap[i] = s; }
        run += tot;
        __syncthreads();
    }
}

// ====== grouped GEMM (R16 inner loop): 256x256 tile, BK=32, 8 waves, per-wave 128x64 ======
// MODE 0 additionally hosts the w2 transpose: blocks >= MAXT0 transpose one 256x128 w2
// tile into w2t using the dynamic-LDS allocation. They dispatch AFTER the GEMM tiles and
// backfill idle CUs during the GEMM's later rounds (GEMM runs at 12% HBM; w2T rides the
// idle BW). Stream order publishes w2t to k_gemm<1>.
template <int MODE>
__global__ __launch_bounds__(512, 2)
void k_gemm(const bf16_t* __restrict__ A,    // MODE0: xb [N][DIM]; MODE1: hbuf [SLOTS][HID]
            const bf16_t* __restrict__ Bt,   // MODE0: w1t [E][HID][DIM]; MODE1: w2t [E][OUTD][HID]
            const float* __restrict__ bias,
            const int* __restrict__ tok_ids,
            const int* __restrict__ bases,
            const int* __restrict__ counts,
            const int* __restrict__ tb,      // [NE+1] tile prefix for this mode
            const float* __restrict__ w2,    // MODE0 only: transpose source
            bf16_t* __restrict__ w2t,        // MODE0 only: transpose dest
            bf16_t* __restrict__ Y) {
    constexpr int KD   = (MODE == 0) ? DIM : HID;
    constexpr int ND   = (MODE == 0) ? HID : OUTD;
    constexpr int KLEN = (MODE == 0) ? DIM : (HID / 2);   // 1024 / 2048
    constexpr int KT   = KLEN / 32;                       // 32 / 64
    constexpr int BUFE = 16384;               // A 8192 + B 8192 elems (32 KiB)

    extern __shared__ bf16_t lds[];           // 96 KiB dynamic

    if (MODE == 0 && blockIdx.x >= MAXT0) {   // ---- hosted w2 transpose block ----
        int b2 = blockIdx.x - MAXT0;          // 0..1023
        int e = b2 >> 7, rem = b2 & 127;      // 16 ry x 8 cx
        tr_tile(w2 + (size_t)e * HID * OUTD, w2t + (size_t)e * HID * OUTD,
                HID, OUTD, rem >> 3, rem & 7,
                (bf16_t(*)[264])lds, threadIdx.x);
        return;
    }

    const int ti = blockIdx.x;
    if (ti >= tb[NE]) return;
    int e = 0;
#pragma unroll
    for (int k = 1; k < NE; ++k) if (ti >= tb[k]) e = k;
    const int local = ti - tb[e];
    const int ne = counts[e];
    const int b0 = bases[e];
    int panel, y, kslot = 0;
    if (MODE == 0) { y = local >> 4; panel = local & 15; }
    else           { y = local >> 3; int q = local & 7; panel = q >> 1; kslot = q & 1; }
    const int m0 = y * 256, n0 = panel * 256;
    const int koff = (MODE == 0) ? 0 : kslot * KLEN;
    bf16_t* __restrict__ Yw = (MODE == 0) ? Y : (Y + (size_t)kslot * SLOTS * OUTD);

    const int t = threadIdx.x, w = t >> 6, L = t & 63;
    const int wm = w >> 2, wn = w & 3;        // 2M x 4N; per-wave out 128x64
    const int lr = L & 15, lq = L >> 4;
    const int srow  = L >> 2;
    const int sslot = L & 3;

    int offA[8], offB[4];
#pragma unroll
    for (int i = 0; i < 8; ++i) {
        int r = wm * 128 + i * 16 + lr;
        offA[i] = r * 32 + ((lq ^ ((r >> 1) & 3)) << 3);
    }
#pragma unroll
    for (int j = 0; j < 4; ++j) {
        int r = wn * 64 + j * 16 + lr;
        offB[j] = 8192 + r * 32 + ((lq ^ ((r >> 1) & 3)) << 3);
    }
    int sdstA[2], sdstB[2];
#pragma unroll
    for (int g = 0; g < 2; ++g) {
        sdstA[g] = (g * 128 + w * 16) * 32;
        sdstB[g] = 8192 + (g * 128 + w * 16) * 32;
    }

#define GLL(srcp, dste) __builtin_amdgcn_global_load_lds( \
        (const __attribute__((address_space(1))) uint32_t*)(srcp), \
        (__attribute__((address_space(3))) uint32_t*)(lds + (dste)), 16, 0, 0)
#define STAGE(Tt, bsl) { \
        _Pragma("unroll") for (int g_ = 0; g_ < 2; ++g_) { \
            GLL(aptr[g_] + (Tt) * 32, (bsl) * BUFE + sdstA[g_]); \
            GLL(bptr[g_] + (Tt) * 32, (bsl) * BUFE + sdstB[g_]); } }

    const bf16_t* aptr[2];
    const bf16_t* bptr[2];
#pragma unroll
    for (int g = 0; g < 2; ++g) {
        int row = g * 128 + w * 16 + srow;
        int gk  = sslot ^ ((row >> 1) & 3);
        int mm = m0 + row;
        int rr = (mm < ne) ? mm : (ne - 1);
        size_t arow = (MODE == 0) ? (size_t)tok_ids[b0 + rr] * KD : (size_t)(b0 + rr) * KD;
        aptr[g] = A + arow + koff + gk * 8;
        bptr[g] = Bt + ((size_t)e * ND + n0 + row) * KD + koff + gk * 8;
    }

    f32x4 acc[8][4];
#pragma unroll
    for (int i = 0; i < 8; ++i)
#pragma unroll
        for (int j = 0; j < 4; ++j) acc[i][j] = (f32x4){0.f, 0.f, 0.f, 0.f};

    STAGE(0, 0); STAGE(1, 1);

    int cb = 0;
    int nb = 2;
    for (int T = 0; T < KT; ++T) {
        if (T < KT - 1) { asm volatile("s_waitcnt vmcnt(4)" ::: "memory"); }
        else            { asm volatile("s_waitcnt vmcnt(0)" ::: "memory"); }
        __builtin_amdgcn_s_barrier();
        if (T + 2 < KT) STAGE(T + 2, nb);

        bf16x8 fb[4], fa[8];
#pragma unroll
        for (int j = 0; j < 4; ++j) fb[j] = *(const bf16x8*)(lds + cb * BUFE + offB[j]);
#pragma unroll
        for (int i = 0; i < 4; ++i) fa[i] = *(const bf16x8*)(lds + cb * BUFE + offA[i]);
        __builtin_amdgcn_sched_barrier(0);
#pragma unroll
        for (int i = 4; i < 8; ++i) fa[i] = *(const bf16x8*)(lds + cb * BUFE + offA[i]);
        __builtin_amdgcn_sched_barrier(0);
        asm volatile("s_waitcnt lgkmcnt(4)" ::: "memory");   // fb + fa0-3 done
        __builtin_amdgcn_sched_barrier(0);
        __builtin_amdgcn_s_setprio(1);
#pragma unroll
        for (int i = 0; i < 4; ++i)
#pragma unroll
            for (int j = 0; j < 4; ++j)
                acc[i][j] = __builtin_amdgcn_mfma_f32_16x16x32_bf16(fb[j], fa[i], acc[i][j], 0, 0, 0);
        __builtin_amdgcn_s_setprio(0);
        asm volatile("s_waitcnt lgkmcnt(0)" ::: "memory");   // fa4-7 done (hidden under mh0)
        __builtin_amdgcn_sched_barrier(0);
        __builtin_amdgcn_s_setprio(1);
#pragma unroll
        for (int i = 4; i < 8; ++i)
#pragma unroll
            for (int j = 0; j < 4; ++j)
                acc[i][j] = __builtin_amdgcn_mfma_f32_16x16x32_bf16(fb[j], fa[i], acc[i][j], 0, 0, 0);
        __builtin_amdgcn_s_setprio(0);

        cb = (cb == 2) ? 0 : cb + 1;
        nb = (nb == 2) ? 0 : nb + 1;
    }

    // ---------------- epilogue: bf16 store ----------------
    const int kbias = (MODE == 0) ? 1 : (kslot == 0 ? 1 : 0);
#pragma unroll
    for (int i = 0; i < 8; ++i) {
        int gm = m0 + wm * 128 + i * 16 + lr;
        if (gm < ne) {
#pragma unroll
            for (int j = 0; j < 4; ++j) {
                int gn = n0 + wn * 64 + j * 16 + lq * 4;
                f32x4 bv = *(const f32x4*)&bias[(size_t)e * ND + gn];
                bf16x4 hv;
#pragma unroll
                for (int r = 0; r < 4; ++r) {
                    float v = acc[i][j][r];
                    if (kbias) v += bv[r];
                    if (MODE == 0) v = fmaxf(v, 0.f);
                    hv[r] = (__bf16)v;
                }
                *(bf16x4*)&Yw[(size_t)(b0 + gm) * ND + gn] = hv;
            }
        }
    }
#undef STAGE
#undef GLL
}

// ---------------- combine: out[n] = g0*(y0a+y0b) + g1*(y1a+y1b) (fp32) ----------------
__global__ void k_combine(const bf16_t* __restrict__ ybuf,   // [2][SLOTS][OUTD]
                          const int* __restrict__ slotmap,
                          const float* __restrict__ tkg,
                          float* __restrict__ out) {
    int n = blockIdx.x;
    int d = threadIdx.x * 4;
    int s0 = slotmap[2 * n], s1 = slotmap[2 * n + 1];
    float g0 = tkg[2 * n],  g1 = tkg[2 * n + 1];
    const bf16_t* y2 = ybuf + (size_t)SLOTS * OUTD;
    bf16x4 a0 = *(const bf16x4*)&ybuf[(size_t)s0 * OUTD + d];
    bf16x4 a1 = *(const bf16x4*)&y2  [(size_t)s0 * OUTD + d];
    bf16x4 c0 = *(const bf16x4*)&ybuf[(size_t)s1 * OUTD + d];
    bf16x4 c1 = *(const bf16x4*)&y2  [(size_t)s1 * OUTD + d];
    f32x4 o;
#pragma unroll
    for (int r = 0; r < 4; ++r)
        o[r] = g0 * ((float)a0[r] + (float)a1[r]) + g1 * ((float)c0[r] + (float)c1[r]);
    *(f32x4*)&out[(size_t)n * OUTD + d] = o;
}

extern "C" void kernel_launch(void* const* d_in, const int* in_sizes, int n_in,
                              void* d_out, int out_size, void* d_ws, size_t ws_size,
                              hipStream_t stream) {
    const float* x  = (const float*)d_in[0];
    const float* wg = (const float*)d_in[1];
    const float* w1 = (const float*)d_in[2];
    const float* b1 = (const float*)d_in[3];
    const float* w2 = (const float*)d_in[4];
    const float* b2 = (const float*)d_in[5];
    float* out = (float*)d_out;

    char* ws = (char*)d_ws;
    size_t o = 0;
    auto alloc = [&](size_t b) { size_t r = o; o = (o + b + 255) & ~(size_t)255; return r; };
    int*    counts  = (int*)(ws + alloc(NE * 4));
    int*    bases   = (int*)(ws + alloc(NE * 4));
    int*    tb0     = (int*)(ws + alloc((NE + 1) * 4));
    int*    tb1     = (int*)(ws + alloc((NE + 1) * 4));
    int*    tki     = (int*)(ws + alloc(SLOTS * 4));
    float*  tkg     = (float*)(ws + alloc(SLOTS * 4));
    int*    tok_ids = (int*)(ws + alloc(SLOTS * 4));
    int*    slotmap = (int*)(ws + alloc(SLOTS * 4));
    bf16_t* xb      = (bf16_t*)(ws + alloc((size_t)N_TOK * DIM * 2));
    size_t  w1t_off = alloc((size_t)NE * HID * DIM * 2);
    bf16_t* w1t     = (bf16_t*)(ws + w1t_off);
    bf16_t* ybuf    = (bf16_t*)(ws + w1t_off);   // [2][SLOTS][OUTD] aliases w1t (dead after GEMM-1)
    bf16_t* w2t     = (bf16_t*)(ws + alloc((size_t)NE * OUTD * HID * 2));
    bf16_t* hbuf    = (bf16_t*)(ws + alloc((size_t)SLOTS * HID * 2));
    (void)ws_size; (void)n_in; (void)in_sizes;

    hipFuncSetAttribute((const void*)&k_gemm<0>, hipFuncAttributeMaxDynamicSharedMemorySize, 98304);
    hipFuncSetAttribute((const void*)&k_gemm<1>, hipFuncAttributeMaxDynamicSharedMemorySize, 98304);

    // prep: w1 transpose (1024) + gating (512); w2 transpose rides inside k_gemm<0>
    k_prep<<<1024 + 512, 512, 0, stream>>>(x, wg, w1, xb, w1t, tki, tkg);
    k_route<<<NE, 256, 0, stream>>>(tki, tkg, counts, bases, tb0, tb1,
                                    out + (size_t)N_TOK * OUTD, tok_ids, slotmap);

    // GEMM-1 tiles (0..MAXT0-1) + hosted w2-transpose blocks (MAXT0..MAXT0+1023)
    k_gemm<0><<<MAXT0 + W2TB, 512, 98304, stream>>>(
        xb, w1t, b1, tok_ids, bases, counts, tb0, w2, w2t, hbuf);
    k_gemm<1><<<MAXT1, 512, 98304, stream>>>(
        hbuf, w2t, b2, tok_ids, bases, counts, tb1, nullptr, nullptr, ybuf);

    k_combine<<<N_TOK, 256, 0, stream>>>(ybuf, slotmap, tkg, out);
}